// Round 6
// baseline (705.186 us; speedup 1.0000x reference)
//
#include <hip/hip_runtime.h>

#define EMB 256
typedef unsigned short u16;
typedef __attribute__((ext_vector_type(8))) short short8v;
typedef __attribute__((ext_vector_type(4))) short short4v;
typedef __attribute__((ext_vector_type(4))) float f32x4;

__device__ inline u16 f2bf(float x){
  union{float f; unsigned u;} c; c.f = x;
  unsigned r = c.u + 0x7FFFu + ((c.u>>16)&1u);
  return (u16)(r>>16);
}
__device__ inline float bf2f(u16 h){
  union{unsigned u; float f;} c; c.u = ((unsigned)h) << 16; return c.f;
}
__device__ inline short8v pack8(float4 a, float4 b){
  short8v v;
  v[0]=(short)f2bf(a.x); v[1]=(short)f2bf(a.y); v[2]=(short)f2bf(a.z); v[3]=(short)f2bf(a.w);
  v[4]=(short)f2bf(b.x); v[5]=(short)f2bf(b.y); v[6]=(short)f2bf(b.z); v[7]=(short)f2bf(b.w);
  return v;
}

// ---------------- DDE: counts + round-1 scatter fused ----------------
__global__ void k_scatter1(const int* __restrict__ h_id, const int* __restrict__ t_id,
                           const float* __restrict__ topic,
                           float* __restrict__ cnt_f, float* __restrict__ cnt_r,
                           float* __restrict__ accf, float* __restrict__ accr, int E) {
  int e = blockIdx.x * 256 + threadIdx.x;
  if (e >= E) return;
  int h = h_id[e], t = t_id[e];
  atomicAdd(&cnt_f[t], 1.0f);
  atomicAdd(&cnt_r[h], 1.0f);
  float a0 = topic[2*h+0], a1 = topic[2*h+1];
  if (a0 != 0.f) atomicAdd(&accf[2*t+0], a0);
  if (a1 != 0.f) atomicAdd(&accf[2*t+1], a1);
  float c0 = topic[2*t+0], c1 = topic[2*t+1];
  if (c0 != 0.f) atomicAdd(&accr[2*h+0], c0);
  if (c1 != 0.f) atomicAdd(&accr[2*h+1], c1);
}

__global__ void k_div1(const float* __restrict__ topic,
                       const float* __restrict__ cnt_f, const float* __restrict__ cnt_r,
                       const float* __restrict__ accf, const float* __restrict__ accr,
                       float* __restrict__ pos, int N) {
  int n = blockIdx.x * 256 + threadIdx.x;
  if (n >= N) return;
  float cf = fmaxf(cnt_f[n], 1.0f), cr = fmaxf(cnt_r[n], 1.0f);
  pos[10*n+0] = topic[2*n+0];
  pos[10*n+1] = topic[2*n+1];
  pos[10*n+2] = accf[2*n+0] / cf;
  pos[10*n+3] = accf[2*n+1] / cf;
  pos[10*n+6] = accr[2*n+0] / cr;
  pos[10*n+7] = accr[2*n+1] / cr;
}

__global__ void k_scatter2(const int* __restrict__ h_id, const int* __restrict__ t_id,
                           const float* __restrict__ pos,
                           float* __restrict__ accf, float* __restrict__ accr, int E) {
  int e = blockIdx.x * 256 + threadIdx.x;
  if (e >= E) return;
  int h = h_id[e], t = t_id[e];
  float a0 = pos[10*h+2], a1 = pos[10*h+3];
  if (a0 != 0.f) atomicAdd(&accf[2*t+0], a0);
  if (a1 != 0.f) atomicAdd(&accf[2*t+1], a1);
  float c0 = pos[10*t+6], c1 = pos[10*t+7];
  if (c0 != 0.f) atomicAdd(&accr[2*h+0], c0);
  if (c1 != 0.f) atomicAdd(&accr[2*h+1], c1);
}

__global__ void k_div2(const float* __restrict__ cnt_f, const float* __restrict__ cnt_r,
                       const float* __restrict__ accf, const float* __restrict__ accr,
                       float* __restrict__ pos, int N) {
  int n = blockIdx.x * 256 + threadIdx.x;
  if (n >= N) return;
  float cf = fmaxf(cnt_f[n], 1.0f), cr = fmaxf(cnt_r[n], 1.0f);
  pos[10*n+4] = accf[2*n+0] / cf;
  pos[10*n+5] = accf[2*n+1] / cf;
  pos[10*n+8] = accr[2*n+0] / cr;
  pos[10*n+9] = accr[2*n+1] / cr;
}

// ---------------- gate softmax + qpart = b1 + q @ W1[:256,:] ----------------
__global__ void k_gate(const float* __restrict__ q, const float* __restrict__ Wg,
                       const float* __restrict__ bg, const float* __restrict__ W1,
                       const float* __restrict__ b1, float* __restrict__ gateq) {
  __shared__ float qs[256];
  __shared__ float z[3];
  int t = threadIdx.x;
  qs[t] = q[t];
  __syncthreads();
  if (t < 3) {
    float s = bg[t];
    for (int k = 0; k < 256; ++k) s += qs[k] * Wg[k*3 + t];
    z[t] = s;
  }
  __syncthreads();
  if (t == 0) {
    float m = fmaxf(z[0], fmaxf(z[1], z[2]));
    float e0 = expf(z[0]-m), e1 = expf(z[1]-m), e2 = expf(z[2]-m);
    float s = e0 + e1 + e2;
    gateq[0] = e0/s; gateq[1] = e1/s; gateq[2] = e2/s; gateq[3] = 0.f;
  }
  float a = b1[t];
  for (int k = 0; k < 256; ++k) a += qs[k] * W1[k*256 + t];
  gateq[4 + t] = a;
}

// ---------------- weight transform: MFMA A-fragment layout, bf16 ----------------
// 35 kt-chunks of K=32: [0..15]=W_nb(512), [16]=W_pos(20,zero-pad),
// [17..26]=W_str(320), [27..34]=W1[256:512].
// A-frag: lane l <-> (feature ft*16+(l&15), k = (l>>4)*8+j). Slot ((kt*16+ft)*64+l)*8+j.
__global__ void k_wtrans(const float* __restrict__ Wnb, const float* __restrict__ Wpos,
                         const float* __restrict__ Wstr, const float* __restrict__ W1,
                         u16* __restrict__ WB) {
  int gid = blockIdx.x * 256 + threadIdx.x;
  if (gid >= 35*16*64) return;
  int lane = gid & 63;
  int ft   = (gid >> 6) & 15;
  int kt   = gid >> 10;
  const float* src; int kbase, klim;
  if (kt < 16)      { src = Wnb;               kbase = kt*32;      klim = 512; }
  else if (kt==16)  { src = Wpos;              kbase = 0;          klim = 20;  }
  else if (kt < 27) { src = Wstr;              kbase = (kt-17)*32; klim = 320; }
  else              { src = W1 + 256*256;      kbase = (kt-27)*32; klim = 256; }
  int n  = ft*16 + (lane & 15);
  int k0 = kbase + (lane >> 4) * 8;
  short8v v;
  #pragma unroll
  for (int j = 0; j < 8; ++j) {
    int k = k0 + j;
    v[j] = (k < klim) ? (short)f2bf(src[(size_t)k*256 + n]) : (short)0;
  }
  *(short8v*)(WB + (size_t)gid * 8) = v;
}

// ---------------- fused MFMA main kernel: 128 edges/block, 8 waves ----------------
// Operand-swapped: D[feature][edge] = W(A) x X^T(B). 8 waves = 4(M=feat) x 2(N=edge).
// Pipelined: X gathered 2 chunks ahead (regs), W fragments 1 chunk ahead (regs),
// XB double-buffered -> ONE barrier per chunk.
__global__ __launch_bounds__(512) __attribute__((amdgpu_waves_per_eu(2)))
void k_main(
    const int* __restrict__ h_id, const int* __restrict__ r_id, const int* __restrict__ t_id,
    const float* __restrict__ ent, const float* __restrict__ ntx,
    const float* __restrict__ rel,
    const int* __restrict__ mids, const float* __restrict__ mwts,
    const float* __restrict__ motif,
    const float* __restrict__ b_nb, const float* __restrict__ b_pos, const float* __restrict__ b_str,
    const float* __restrict__ W2, const float* __restrict__ b2,
    const float* __restrict__ pos, const float* __restrict__ gateq,
    const u16* __restrict__ WBg,
    float* __restrict__ out, int E, int NT)
{
  __shared__ __align__(16) u16 XB[2][8*64*8];    // X chunk dbuf (8 KB each)
  __shared__ __align__(16) u16 FT2[8*8*64*8];    // fused [k=256][edge=128] frag order (64 KB)
  __shared__ float woacc[4][128];                // layer-2 per-Mw partials (2 KB)

  const int t  = threadIdx.x;
  const int wv = t >> 6, l = t & 63;
  const int Mw = wv >> 1, Nw = wv & 1;           // 4 x 2 wave grid
  const int lr = l & 15, lg = l >> 4;
  const int be = blockIdx.x * 128;
  const int se = wv * 16 + lr;                   // staging edge row 0..127
  const int sko = lg * 8;                        // staging k offset

  // per-thread edge ids (row se)
  int e_r = be + se; if (e_r >= E) e_r = E - 1;
  const int hid = h_id[e_r], tid = t_id[e_r], rid = r_id[e_r];
  const float* hrow = (hid < NT) ? (ent + (size_t)hid * EMB) : ntx;
  const float* trow = (tid < NT) ? (ent + (size_t)tid * EMB) : ntx;
  const float* rrow = rel + (size_t)rid * EMB;

  const float g0 = gateq[0], g1 = gateq[1], g2 = gateq[2];

  f32x4 acc[4][4];
  short8v xpa, xpb;        // X prefetch regs: chunk c+1, c+2
  short8v afc[4], afn[4];  // W fragments: current chunk, next chunk

  auto zacc = [&]() {
    #pragma unroll
    for (int m = 0; m < 4; ++m)
      #pragma unroll
      for (int n = 0; n < 4; ++n)
        acc[m][n] = (f32x4){0.f, 0.f, 0.f, 0.f};
  };

  auto wload = [&](int kt, short8v* dst) {
    const u16* wc = WBg + (size_t)kt * 8192;
    #pragma unroll
    for (int m = 0; m < 4; ++m)
      dst[m] = *(const short8v*)&wc[((Mw*4 + m)*64 + l) * 8];
  };

  // gather X chunk c's slice for this thread
  auto xload = [&](int c, short8v& dst) {
    if (c < 16) {
      const float* src = ((c < 8) ? hrow : trow) + (c & 7) * 32 + sko;
      dst = pack8(*(const float4*)src, *(const float4*)(src + 4));
    } else if (c == 16) {
      float vals[8];
      #pragma unroll
      for (int j = 0; j < 8; ++j) {
        int k = sko + j;
        vals[j] = (k < 10) ? pos[(size_t)hid*10 + k]
                : (k < 20) ? pos[(size_t)tid*10 + (k - 10)] : 0.f;
      }
      short8v v;
      #pragma unroll
      for (int j = 0; j < 8; ++j) v[j] = (short)f2bf(vals[j]);
      dst = v;
    } else if (c < 25) {
      const float* src = rrow + (c - 17) * 32 + sko;
      dst = pack8(*(const float4*)src, *(const float4*)(src + 4));
    } else {  // 25, 26: motif weighted sum over 8 tokens, dims d0..d0+8
      int d0 = (c - 25) * 32 + sko;
      float s[8] = {0,0,0,0,0,0,0,0};
      #pragma unroll
      for (int j = 0; j < 8; ++j) {
        int id = mids[(size_t)e_r*8 + j];
        float wj = mwts[(size_t)e_r*8 + j];
        if (id != 0) {
          const float* mr = motif + (size_t)id*64 + d0;
          #pragma unroll
          for (int i = 0; i < 8; ++i) s[i] = fmaf(mr[i], wj, s[i]);
        }
      }
      short8v v;
      #pragma unroll
      for (int i = 0; i < 8; ++i) v[i] = (short)f2bf(s[i]);
      dst = v;
    }
  };

  // channel result -> FT2 (bf16 frag order), wave-private RMW accumulate
  auto combine = [&](const float* bias, float g, bool first) {
    #pragma unroll
    for (int m = 0; m < 4; ++m) {
      int f0 = Mw*64 + m*16 + lg*4;
      float bv0 = bias[f0+0], bv1 = bias[f0+1], bv2 = bias[f0+2], bv3 = bias[f0+3];
      int kc  = Mw*2 + ((m*4 + lg) >> 3);
      int lg2 = (m*2 + (lg >> 1)) & 3;
      #pragma unroll
      for (int n = 0; n < 4; ++n) {
        int nt = Nw*4 + n;
        int idx = ((kc*8 + nt)*64 + lg2*16 + lr)*8 + (lg & 1)*4;
        float v0 = g * fmaxf(acc[m][n][0] + bv0, 0.f);
        float v1 = g * fmaxf(acc[m][n][1] + bv1, 0.f);
        float v2 = g * fmaxf(acc[m][n][2] + bv2, 0.f);
        float v3 = g * fmaxf(acc[m][n][3] + bv3, 0.f);
        if (!first) {
          short4v o = *(short4v*)&FT2[idx];
          v0 += bf2f((u16)o[0]); v1 += bf2f((u16)o[1]);
          v2 += bf2f((u16)o[2]); v3 += bf2f((u16)o[3]);
        }
        short4v w;
        w[0] = (short)f2bf(v0); w[1] = (short)f2bf(v1);
        w[2] = (short)f2bf(v2); w[3] = (short)f2bf(v3);
        *(short4v*)&FT2[idx] = w;
      }
    }
  };

  // ===== prologue: chunk 0 -> XB[0]; chunk 1 gather in flight; W(0) in flight =====
  zacc();
  xload(0, xpa);
  wload(0, afc);
  *(short8v*)&XB[0][t * 8] = xpa;
  xload(1, xpa);
  __syncthreads();

  // ===== channel chunks: c = 0..26 (ch1: 0-15, ch2: 16, ch3: 17-26) =====
  for (int c = 0; c < 27; ++c) {
    const int cur = c & 1;
    wload(c + 1, afn);                       // W prefetch (27 on last iter feeds layer-1)
    if (c + 2 <= 26) xload(c + 2, xpb);      // X gather 2 ahead
    short8v bfr[4];
    #pragma unroll
    for (int n = 0; n < 4; ++n)
      bfr[n] = *(const short8v*)&XB[cur][((Nw*4 + n)*64 + l) * 8];
    #pragma unroll
    for (int m = 0; m < 4; ++m)
      #pragma unroll
      for (int n = 0; n < 4; ++n)
        acc[m][n] = __builtin_amdgcn_mfma_f32_16x16x32_bf16(afc[m], bfr[n], acc[m][n], 0, 0, 0);
    if (c == 15)      { combine(b_nb,  g0, true);  zacc(); }
    else if (c == 16) { combine(b_pos, g1, false); zacc(); }
    if (c < 26)
      *(short8v*)&XB[cur ^ 1][t * 8] = xpa;  // write-late: chunk c+1 into other buffer
    __syncthreads();                          // single barrier per chunk
    xpa = xpb;
    #pragma unroll
    for (int m = 0; m < 4; ++m) afc[m] = afn[m];
  }
  combine(b_str, g2, false);

  // ===== layer 1: acc init = qpart (b1 + q@W1_top), B = FT2, W1 kt 27..34 =====
  #pragma unroll
  for (int m = 0; m < 4; ++m) {
    int f0 = Mw*64 + m*16 + lg*4;
    f32x4 qv = { gateq[4+f0], gateq[5+f0], gateq[6+f0], gateq[7+f0] };
    #pragma unroll
    for (int n = 0; n < 4; ++n) acc[m][n] = qv;
  }
  __syncthreads();                            // FT2 fully written (cross-wave reads next)
  for (int c2 = 0; c2 < 8; ++c2) {
    if (c2 < 7) wload(28 + c2, afn);
    short8v bfr[4];
    #pragma unroll
    for (int n = 0; n < 4; ++n)
      bfr[n] = *(const short8v*)&FT2[((c2*8 + Nw*4 + n)*64 + l) * 8];
    #pragma unroll
    for (int m = 0; m < 4; ++m)
      #pragma unroll
      for (int n = 0; n < 4; ++n)
        acc[m][n] = __builtin_amdgcn_mfma_f32_16x16x32_bf16(afc[m], bfr[n], acc[m][n], 0, 0, 0);
    if (c2 < 7) {
      #pragma unroll
      for (int m = 0; m < 4; ++m) afc[m] = afn[m];
    }
  }

  // ===== layer 2: out = relu(act) @ W2 + b2, per-wave partials =====
  {
    float w2v[4][4];
    #pragma unroll
    for (int m = 0; m < 4; ++m) {
      int f0 = Mw*64 + m*16 + lg*4;
      #pragma unroll
      for (int r2 = 0; r2 < 4; ++r2) w2v[m][r2] = W2[f0 + r2];
    }
    #pragma unroll
    for (int n = 0; n < 4; ++n) {
      float p = 0.f;
      #pragma unroll
      for (int m = 0; m < 4; ++m)
        #pragma unroll
        for (int r2 = 0; r2 < 4; ++r2)
          p = fmaf(fmaxf(acc[m][n][r2], 0.f), w2v[m][r2], p);
      p += __shfl_xor(p, 16);
      p += __shfl_xor(p, 32);
      if (lg == 0) woacc[Mw][Nw*64 + n*16 + lr] = p;
    }
  }
  __syncthreads();
  if (t < 128) {
    int e = be + t;
    if (e < E)
      out[e] = woacc[0][t] + woacc[1][t] + woacc[2][t] + woacc[3][t] + b2[0];
  }
}

extern "C" void kernel_launch(void* const* d_in, const int* in_sizes, int n_in,
                              void* d_out, int out_size, void* d_ws, size_t ws_size,
                              hipStream_t stream) {
  const int*   h_id  = (const int*)  d_in[0];
  const int*   r_id  = (const int*)  d_in[1];
  const int*   t_id  = (const int*)  d_in[2];
  const float* q     = (const float*)d_in[3];
  const float* ent   = (const float*)d_in[4];
  const float* rel   = (const float*)d_in[6];
  const float* topic = (const float*)d_in[7];
  const int*   mids  = (const int*)  d_in[8];
  const float* mwts  = (const float*)d_in[9];
  const float* ntx   = (const float*)d_in[10];
  const float* motif = (const float*)d_in[11];
  const float* W_nb  = (const float*)d_in[12];
  const float* b_nb  = (const float*)d_in[13];
  const float* W_pos = (const float*)d_in[14];
  const float* b_pos = (const float*)d_in[15];
  const float* W_str = (const float*)d_in[16];
  const float* b_str = (const float*)d_in[17];
  const float* W_g   = (const float*)d_in[18];
  const float* b_g   = (const float*)d_in[19];
  const float* W1    = (const float*)d_in[20];
  const float* b1    = (const float*)d_in[21];
  const float* W2    = (const float*)d_in[22];
  const float* b2    = (const float*)d_in[23];
  float* out = (float*)d_out;

  const int E  = in_sizes[0];
  const int NT = in_sizes[4] / EMB;   // 80000 text entities
  const int N  = in_sizes[7] / 2;     // 100000 total nodes

  float* ws    = (float*)d_ws;
  float* cnt_f = ws;
  float* cnt_r = ws + (size_t)N;
  float* a1f   = ws + (size_t)2*N;
  float* a1r   = ws + (size_t)4*N;
  float* a2f   = ws + (size_t)6*N;
  float* a2r   = ws + (size_t)8*N;
  float* pos   = ws + (size_t)10*N;   // N x 10
  float* gateq = ws + (size_t)20*N;   // [g0,g1,g2,pad, qpart(256)]
  u16*   WBg   = (u16*)(ws + (size_t)20*N + 512);  // 35 chunks x 16KB bf16 frags

  hipMemsetAsync(d_ws, 0, (size_t)10 * N * sizeof(float), stream);

  int gE = (E + 255) / 256, gN = (N + 255) / 256;
  k_scatter1<<<gE, 256, 0, stream>>>(h_id, t_id, topic, cnt_f, cnt_r, a1f, a1r, E);
  k_div1    <<<gN, 256, 0, stream>>>(topic, cnt_f, cnt_r, a1f, a1r, pos, N);
  k_scatter2<<<gE, 256, 0, stream>>>(h_id, t_id, pos, a2f, a2r, E);
  k_div2    <<<gN, 256, 0, stream>>>(cnt_f, cnt_r, a2f, a2r, pos, N);
  k_gate    <<<1, 256, 0, stream>>>(q, W_g, b_g, W1, b1, gateq);
  k_wtrans  <<<140, 256, 0, stream>>>(W_nb, W_pos, W_str, W1, (u16*)WBg);

  int gM = (E + 127) / 128;
  k_main<<<gM, 512, 0, stream>>>(h_id, r_id, t_id, ent, ntx, rel, mids, mwts, motif,
                                 b_nb, b_pos, b_str, W2, b2,
                                 pos, gateq, WBg, out, E, NT);
}

// Round 7
// 466.904 us; speedup vs baseline: 1.5103x; 1.5103x over previous
//
#include <hip/hip_runtime.h>

#define EMB 256
typedef unsigned short u16;
typedef __attribute__((ext_vector_type(8))) short short8v;
typedef __attribute__((ext_vector_type(4))) short short4v;
typedef __attribute__((ext_vector_type(4))) float f32x4;

__device__ inline u16 f2bf(float x){
  union{float f; unsigned u;} c; c.f = x;
  unsigned r = c.u + 0x7FFFu + ((c.u>>16)&1u);
  return (u16)(r>>16);
}
__device__ inline float bf2f(u16 h){
  union{unsigned u; float f;} c; c.u = ((unsigned)h) << 16; return c.f;
}

// ---------------- DDE: counts + round-1 scatter fused ----------------
__global__ void k_scatter1(const int* __restrict__ h_id, const int* __restrict__ t_id,
                           const float* __restrict__ topic,
                           float* __restrict__ cnt_f, float* __restrict__ cnt_r,
                           float* __restrict__ accf, float* __restrict__ accr, int E) {
  int e = blockIdx.x * 256 + threadIdx.x;
  if (e >= E) return;
  int h = h_id[e], t = t_id[e];
  atomicAdd(&cnt_f[t], 1.0f);
  atomicAdd(&cnt_r[h], 1.0f);
  float a0 = topic[2*h+0], a1 = topic[2*h+1];
  if (a0 != 0.f) atomicAdd(&accf[2*t+0], a0);
  if (a1 != 0.f) atomicAdd(&accf[2*t+1], a1);
  float c0 = topic[2*t+0], c1 = topic[2*t+1];
  if (c0 != 0.f) atomicAdd(&accr[2*h+0], c0);
  if (c1 != 0.f) atomicAdd(&accr[2*h+1], c1);
}

__global__ void k_div1(const float* __restrict__ topic,
                       const float* __restrict__ cnt_f, const float* __restrict__ cnt_r,
                       const float* __restrict__ accf, const float* __restrict__ accr,
                       float* __restrict__ pos, int N) {
  int n = blockIdx.x * 256 + threadIdx.x;
  if (n >= N) return;
  float cf = fmaxf(cnt_f[n], 1.0f), cr = fmaxf(cnt_r[n], 1.0f);
  pos[10*n+0] = topic[2*n+0];
  pos[10*n+1] = topic[2*n+1];
  pos[10*n+2] = accf[2*n+0] / cf;
  pos[10*n+3] = accf[2*n+1] / cf;
  pos[10*n+6] = accr[2*n+0] / cr;
  pos[10*n+7] = accr[2*n+1] / cr;
}

__global__ void k_scatter2(const int* __restrict__ h_id, const int* __restrict__ t_id,
                           const float* __restrict__ pos,
                           float* __restrict__ accf, float* __restrict__ accr, int E) {
  int e = blockIdx.x * 256 + threadIdx.x;
  if (e >= E) return;
  int h = h_id[e], t = t_id[e];
  float a0 = pos[10*h+2], a1 = pos[10*h+3];
  if (a0 != 0.f) atomicAdd(&accf[2*t+0], a0);
  if (a1 != 0.f) atomicAdd(&accf[2*t+1], a1);
  float c0 = pos[10*t+6], c1 = pos[10*t+7];
  if (c0 != 0.f) atomicAdd(&accr[2*h+0], c0);
  if (c1 != 0.f) atomicAdd(&accr[2*h+1], c1);
}

__global__ void k_div2(const float* __restrict__ cnt_f, const float* __restrict__ cnt_r,
                       const float* __restrict__ accf, const float* __restrict__ accr,
                       float* __restrict__ pos, int N) {
  int n = blockIdx.x * 256 + threadIdx.x;
  if (n >= N) return;
  float cf = fmaxf(cnt_f[n], 1.0f), cr = fmaxf(cnt_r[n], 1.0f);
  pos[10*n+4] = accf[2*n+0] / cf;
  pos[10*n+5] = accf[2*n+1] / cf;
  pos[10*n+8] = accr[2*n+0] / cr;
  pos[10*n+9] = accr[2*n+1] / cr;
}

// ---------------- gate softmax + qpart = b1 + q @ W1[:256,:] ----------------
__global__ void k_gate(const float* __restrict__ q, const float* __restrict__ Wg,
                       const float* __restrict__ bg, const float* __restrict__ W1,
                       const float* __restrict__ b1, float* __restrict__ gateq) {
  __shared__ float qs[256];
  __shared__ float z[3];
  int t = threadIdx.x;
  qs[t] = q[t];
  __syncthreads();
  if (t < 3) {
    float s = bg[t];
    for (int k = 0; k < 256; ++k) s += qs[k] * Wg[k*3 + t];
    z[t] = s;
  }
  __syncthreads();
  if (t == 0) {
    float m = fmaxf(z[0], fmaxf(z[1], z[2]));
    float e0 = expf(z[0]-m), e1 = expf(z[1]-m), e2 = expf(z[2]-m);
    float s = e0 + e1 + e2;
    gateq[0] = e0/s; gateq[1] = e1/s; gateq[2] = e2/s; gateq[3] = 0.f;
  }
  float a = b1[t];
  for (int k = 0; k < 256; ++k) a += qs[k] * W1[k*256 + t];
  gateq[4 + t] = a;
}

// ---------------- weight transforms ----------------
// WB A-frags (11 chunks of K=32): [0]=W_pos(20), [1,2]=W_str[256:320] (K=64), [3..10]=W1[256:512].
// A-frag: lane l <-> (feat ft*16+(l&15), k=(l>>4)*8+j), slot ((kt*16+ft)*64+l)*8+j.
// WN B-frags for k_node (8 chunks x 32 col-tiles): col = nt*16+(l&15) in [0,512),
// k = kc*32+(l>>4)*8+j; value = col<256 ? W_nb[k][col] : W_nb[256+k][col-256].
__global__ void k_wtrans(const float* __restrict__ Wpos, const float* __restrict__ Wstr,
                         const float* __restrict__ W1, const float* __restrict__ Wnb,
                         u16* __restrict__ WB, u16* __restrict__ WN) {
  int gid = blockIdx.x * 256 + threadIdx.x;
  if (gid < 11*1024) {
    int lane = gid & 63, ft = (gid >> 6) & 15, kt = gid >> 10;
    const float* src; int kbase, klim;
    if (kt == 0)      { src = Wpos;            kbase = 0;          klim = 20;  }
    else if (kt < 3)  { src = Wstr + 256*256;  kbase = (kt-1)*32;  klim = 64;  }
    else              { src = W1 + 256*256;    kbase = (kt-3)*32;  klim = 256; }
    int n  = ft*16 + (lane & 15);
    int k0 = kbase + (lane >> 4) * 8;
    short8v v;
    #pragma unroll
    for (int j = 0; j < 8; ++j) {
      int k = k0 + j;
      v[j] = (k < klim) ? (short)f2bf(src[(size_t)k*256 + n]) : (short)0;
    }
    *(short8v*)(WB + (size_t)gid * 8) = v;
  } else {
    int g2 = gid - 11*1024;
    if (g2 >= 8*32*64) return;
    int lane = g2 & 63, nt = (g2 >> 6) & 31, kc = g2 >> 11;
    int col = nt*16 + (lane & 15);
    int k0  = kc*32 + (lane >> 4) * 8;
    short8v v;
    #pragma unroll
    for (int j = 0; j < 8; ++j) {
      int k = k0 + j;
      float x = (col < 256) ? Wnb[(size_t)k*256 + col] : Wnb[(size_t)(256+k)*256 + (col-256)];
      v[j] = (short)f2bf(x);
    }
    *(short8v*)(WN + (size_t)g2 * 8) = v;
  }
}

// ---------------- S = rel @ W_str_top, f32 [2000][256] ----------------
__global__ void k_S(const float* __restrict__ rel, const float* __restrict__ Wstr,
                    float* __restrict__ S) {
  __shared__ float rs[256];
  int r = blockIdx.x, t = threadIdx.x;
  rs[t] = rel[(size_t)r*256 + t];
  __syncthreads();
  float a = 0.f;
  for (int k = 0; k < 256; ++k) a = fmaf(rs[k], Wstr[(size_t)k*256 + t], a);
  S[(size_t)r*256 + t] = a;
}

// ---------------- node tables: TA[n]=h_e[n]@Wnb_top, TB[n]=h_e[n]@Wnb_bot (bf16) ------
// 64 nodes/block, 8 waves; wave wv owns output cols [wv*64, wv*64+64) of 512.
// Row NT (=80000) is the shared non-text row (from ntx).
__global__ __launch_bounds__(512) void k_node(const float* __restrict__ ent,
                                              const float* __restrict__ ntx,
                                              const u16* __restrict__ WN,
                                              u16* __restrict__ TA, u16* __restrict__ TB,
                                              int NT) {
  __shared__ __align__(16) u16 AF[4*64*8];   // A chunk frags (4 KB)
  __shared__ __align__(16) u16 TT[64*512];   // output tile (64 KB)
  const int t = threadIdx.x, wv = t >> 6, l = t & 63;
  const int lr = l & 15, lg = l >> 4;
  const int nb0 = blockIdx.x * 64;

  // staging assignment: (mt, l2, half)
  const int mt = t >> 7, half = (t >> 6) & 1, l2 = t & 63;
  int snode = nb0 + mt*16 + (l2 & 15);
  const float* srow = (snode < NT) ? (ent + (size_t)snode * EMB) : ntx;

  f32x4 acc[4][4];
  #pragma unroll
  for (int m = 0; m < 4; ++m)
    #pragma unroll
    for (int n = 0; n < 4; ++n) acc[m][n] = (f32x4){0.f,0.f,0.f,0.f};

  for (int kc = 0; kc < 8; ++kc) {
    {
      int k = kc*32 + (l2 >> 4)*8 + half*4;
      float4 a4 = *(const float4*)(srow + k);
      short4v v;
      v[0]=(short)f2bf(a4.x); v[1]=(short)f2bf(a4.y);
      v[2]=(short)f2bf(a4.z); v[3]=(short)f2bf(a4.w);
      *(short4v*)&AF[((mt*64 + l2)*8 + half*4)] = v;
    }
    __syncthreads();
    short8v bn[4], af[4];
    #pragma unroll
    for (int n = 0; n < 4; ++n)
      bn[n] = *(const short8v*)&WN[((size_t)(kc*32 + wv*4 + n)*64 + l)*8];
    #pragma unroll
    for (int m = 0; m < 4; ++m)
      af[m] = *(const short8v*)&AF[(m*64 + l)*8];
    #pragma unroll
    for (int m = 0; m < 4; ++m)
      #pragma unroll
      for (int n = 0; n < 4; ++n)
        acc[m][n] = __builtin_amdgcn_mfma_f32_16x16x32_bf16(af[m], bn[n], acc[m][n], 0, 0, 0);
    __syncthreads();
  }
  // D -> TT: node = m*16+lg*4+r2 (row), col = wv*64+n*16+lr
  #pragma unroll
  for (int m = 0; m < 4; ++m)
    #pragma unroll
    for (int n = 0; n < 4; ++n) {
      int col = wv*64 + n*16 + lr;
      #pragma unroll
      for (int r2 = 0; r2 < 4; ++r2)
        TT[(m*16 + lg*4 + r2)*512 + col] = f2bf(acc[m][n][r2]);
    }
  __syncthreads();
  // TT -> global (coalesced 16B)
  #pragma unroll
  for (int p = 0; p < 8; ++p) {
    int idx = p*512 + t;
    int nrow = idx >> 6, grp = idx & 63, col = grp*8;
    int node = nb0 + nrow;
    if (node <= NT) {
      uint4 v = *(const uint4*)&TT[nrow*512 + col];
      u16* dst = (col < 256) ? (TA + (size_t)node*256 + col)
                             : (TB + (size_t)node*256 + (col-256));
      *(uint4*)dst = v;
    }
  }
}

// ---------------- main kernel: 128 edges/block, 8 waves (4Mw x 2Nw) ----------------
// Channels: pos (1 MFMA chunk) + struct (S gather + 2 motif MFMA chunks) + nb (pure
// gather/VALU RMW from TA/TB tables). Then layer1 (8 chunks) + layer2.
__global__ __launch_bounds__(512) __attribute__((amdgpu_waves_per_eu(2)))
void k_main(
    const int* __restrict__ h_id, const int* __restrict__ r_id, const int* __restrict__ t_id,
    const int* __restrict__ mids, const float* __restrict__ mwts,
    const float* __restrict__ motif,
    const float* __restrict__ b_nb, const float* __restrict__ b_pos, const float* __restrict__ b_str,
    const float* __restrict__ W2, const float* __restrict__ b2,
    const float* __restrict__ pos, const float* __restrict__ gateq,
    const u16* __restrict__ WB, const float* __restrict__ S,
    const u16* __restrict__ TA, const u16* __restrict__ TB,
    float* __restrict__ out, int E, int NT)
{
  __shared__ __align__(16) u16 FT2[8*8*64*8];   // fused [k=256][edge=128] frag order (64 KB)
  __shared__ __align__(16) u16 XB[8*64*8];      // one staged B chunk (8 KB)
  __shared__ int ridsh[128];
  __shared__ float woacc[4][128];

  const int t  = threadIdx.x;
  const int wv = t >> 6, l = t & 63;
  const int Mw = wv >> 1, Nw = wv & 1;
  const int lr = l & 15, lg = l >> 4;
  const int be = blockIdx.x * 128;

  // own edge (producer/staging role)
  int eo = be + wv*16 + lr; if (eo >= E) eo = E - 1;
  const int hid = h_id[eo], tid = t_id[eo];
  if (t < 128) {
    int e = be + t; if (e >= E) e = E - 1;
    ridsh[t] = r_id[e];
  }

  const float g0 = gateq[0], g1 = gateq[1], g2 = gateq[2];

  f32x4 acc[4][4];
  auto zacc = [&]() {
    #pragma unroll
    for (int m = 0; m < 4; ++m)
      #pragma unroll
      for (int n = 0; n < 4; ++n) acc[m][n] = (f32x4){0.f,0.f,0.f,0.f};
  };

  auto mfma_chunk = [&](const u16* wc) {
    short8v af[4], bfr[4];
    #pragma unroll
    for (int m = 0; m < 4; ++m)
      af[m] = *(const short8v*)&wc[((Mw*4 + m)*64 + l)*8];
    #pragma unroll
    for (int n = 0; n < 4; ++n)
      bfr[n] = *(const short8v*)&XB[((Nw*4 + n)*64 + l)*8];
    #pragma unroll
    for (int m = 0; m < 4; ++m)
      #pragma unroll
      for (int n = 0; n < 4; ++n)
        acc[m][n] = __builtin_amdgcn_mfma_f32_16x16x32_bf16(af[m], bfr[n], acc[m][n], 0, 0, 0);
  };

  // ===== pos chunk stage (own slot) =====
  {
    float vals[8];
    #pragma unroll
    for (int j = 0; j < 8; ++j) {
      int k = lg*8 + j;
      vals[j] = (k < 10) ? pos[(size_t)hid*10 + k]
              : (k < 20) ? pos[(size_t)tid*10 + (k - 10)] : 0.f;
    }
    short8v v;
    #pragma unroll
    for (int j = 0; j < 8; ++j) v[j] = (short)f2bf(vals[j]);
    *(short8v*)&XB[(wv*64 + l)*8] = v;
  }
  zacc();
  __syncthreads();
  mfma_chunk(WB);                                  // chunk 0 = W_pos
  // combine pos -> FT2 (write, first)
  {
    #pragma unroll
    for (int m = 0; m < 4; ++m) {
      int f0 = Mw*64 + m*16 + lg*4;
      float4 bs = *(const float4*)&b_pos[f0];
      int kc  = Mw*2 + ((m*4 + lg) >> 3);
      int lg2 = (m*2 + (lg >> 1)) & 3;
      #pragma unroll
      for (int n = 0; n < 4; ++n) {
        int nt = Nw*4 + n;
        int idx = ((kc*8 + nt)*64 + lg2*16 + lr)*8 + (lg & 1)*4;
        short4v w;
        w[0] = (short)f2bf(g1 * fmaxf(acc[m][n][0] + bs.x, 0.f));
        w[1] = (short)f2bf(g1 * fmaxf(acc[m][n][1] + bs.y, 0.f));
        w[2] = (short)f2bf(g1 * fmaxf(acc[m][n][2] + bs.z, 0.f));
        w[3] = (short)f2bf(g1 * fmaxf(acc[m][n][3] + bs.w, 0.f));
        *(short4v*)&FT2[idx] = w;
      }
    }
  }
  zacc();
  __syncthreads();                                 // all waves done with XB

  // ===== motif: 2 chunks (K=64) =====
  int mid8[8]; float mw8[8];
  #pragma unroll
  for (int j = 0; j < 8; ++j) {
    mid8[j] = mids[(size_t)eo*8 + j];
    mw8[j]  = mwts[(size_t)eo*8 + j];
  }
  auto stage_motif = [&](int cc) {
    int d0 = cc*32 + lg*8;
    float s[8] = {0,0,0,0,0,0,0,0};
    #pragma unroll
    for (int jt = 0; jt < 8; ++jt) {
      if (mid8[jt] != 0) {
        const float* mr = motif + (size_t)mid8[jt]*64 + d0;
        float wt = mw8[jt];
        #pragma unroll
        for (int i = 0; i < 8; ++i) s[i] = fmaf(mr[i], wt, s[i]);
      }
    }
    short8v v;
    #pragma unroll
    for (int i = 0; i < 8; ++i) v[i] = (short)f2bf(s[i]);
    *(short8v*)&XB[(wv*64 + l)*8] = v;
  };
  stage_motif(0);
  __syncthreads();
  mfma_chunk(WB + 1*8192);
  __syncthreads();
  stage_motif(1);
  __syncthreads();
  mfma_chunk(WB + 2*8192);
  // combine struct: S gather (L2-hot) + b_str, RMW FT2
  {
    #pragma unroll
    for (int m = 0; m < 4; ++m) {
      int f0 = Mw*64 + m*16 + lg*4;
      float4 bs = *(const float4*)&b_str[f0];
      int kc  = Mw*2 + ((m*4 + lg) >> 3);
      int lg2 = (m*2 + (lg >> 1)) & 3;
      #pragma unroll
      for (int n = 0; n < 4; ++n) {
        int nt = Nw*4 + n;
        int r = ridsh[nt*16 + lr];
        float4 sv = *(const float4*)&S[(size_t)r*256 + f0];
        int idx = ((kc*8 + nt)*64 + lg2*16 + lr)*8 + (lg & 1)*4;
        short4v o = *(const short4v*)&FT2[idx];
        short4v w;
        w[0] = (short)f2bf(bf2f((u16)o[0]) + g2 * fmaxf(acc[m][n][0] + sv.x + bs.x, 0.f));
        w[1] = (short)f2bf(bf2f((u16)o[1]) + g2 * fmaxf(acc[m][n][1] + sv.y + bs.y, 0.f));
        w[2] = (short)f2bf(bf2f((u16)o[2]) + g2 * fmaxf(acc[m][n][2] + sv.z + bs.z, 0.f));
        w[3] = (short)f2bf(bf2f((u16)o[3]) + g2 * fmaxf(acc[m][n][3] + sv.w + bs.w, 0.f));
        *(short4v*)&FT2[idx] = w;
      }
    }
  }
  __syncthreads();                                 // FT2 pos+str complete

  // ===== nb channel: gather TA[h]/TB[t] (bf16), RMW own FT2 slots =====
  {
    const u16* pa = TA + (size_t)((hid < NT) ? hid : NT) * 256;
    const u16* pb = TB + (size_t)((tid < NT) ? tid : NT) * 256;
    #pragma unroll
    for (int kk = 0; kk < 8; kk += 4) {
      short8v la[4], lb[4];
      #pragma unroll
      for (int c2 = 0; c2 < 4; ++c2) {
        la[c2] = *(const short8v*)(pa + (kk + c2)*32 + lg*8);
        lb[c2] = *(const short8v*)(pb + (kk + c2)*32 + lg*8);
      }
      #pragma unroll
      for (int c2 = 0; c2 < 4; ++c2) {
        int kc = kk + c2;
        int k0 = kc*32 + lg*8;
        float4 bb0 = *(const float4*)&b_nb[k0];
        float4 bb1 = *(const float4*)&b_nb[k0 + 4];
        float bn[8] = {bb0.x,bb0.y,bb0.z,bb0.w,bb1.x,bb1.y,bb1.z,bb1.w};
        u16* slot = &FT2[((kc*8 + wv)*64 + l)*8];
        short8v o = *(const short8v*)slot;
        short8v w;
        #pragma unroll
        for (int j = 0; j < 8; ++j) {
          float v = bf2f((u16)o[j]) +
                    g0 * fmaxf(bf2f((u16)la[c2][j]) + bf2f((u16)lb[c2][j]) + bn[j], 0.f);
          w[j] = (short)f2bf(v);
        }
        *(short8v*)slot = w;
      }
    }
  }

  // ===== layer 1: acc init = qpart, B = FT2, A = W1 chunks 3..10 =====
  #pragma unroll
  for (int m = 0; m < 4; ++m) {
    int f0 = Mw*64 + m*16 + lg*4;
    f32x4 qv = { gateq[4+f0], gateq[5+f0], gateq[6+f0], gateq[7+f0] };
    #pragma unroll
    for (int n = 0; n < 4; ++n) acc[m][n] = qv;
  }
  __syncthreads();                                 // FT2 final, visible to all
  for (int c2 = 0; c2 < 8; ++c2) {
    const u16* wc = WB + (size_t)(3 + c2) * 8192;
    short8v af[4], bfr[4];
    #pragma unroll
    for (int m = 0; m < 4; ++m)
      af[m] = *(const short8v*)&wc[((Mw*4 + m)*64 + l)*8];
    #pragma unroll
    for (int n = 0; n < 4; ++n)
      bfr[n] = *(const short8v*)&FT2[((c2*8 + Nw*4 + n)*64 + l)*8];
    #pragma unroll
    for (int m = 0; m < 4; ++m)
      #pragma unroll
      for (int n = 0; n < 4; ++n)
        acc[m][n] = __builtin_amdgcn_mfma_f32_16x16x32_bf16(af[m], bfr[n], acc[m][n], 0, 0, 0);
  }

  // ===== layer 2 =====
  {
    float w2v[4][4];
    #pragma unroll
    for (int m = 0; m < 4; ++m) {
      int f0 = Mw*64 + m*16 + lg*4;
      #pragma unroll
      for (int r2 = 0; r2 < 4; ++r2) w2v[m][r2] = W2[f0 + r2];
    }
    #pragma unroll
    for (int n = 0; n < 4; ++n) {
      float p = 0.f;
      #pragma unroll
      for (int m = 0; m < 4; ++m)
        #pragma unroll
        for (int r2 = 0; r2 < 4; ++r2)
          p = fmaf(fmaxf(acc[m][n][r2], 0.f), w2v[m][r2], p);
      p += __shfl_xor(p, 16);
      p += __shfl_xor(p, 32);
      if (lg == 0) woacc[Mw][Nw*64 + n*16 + lr] = p;
    }
  }
  __syncthreads();
  if (t < 128) {
    int e = be + t;
    if (e < E)
      out[e] = woacc[0][t] + woacc[1][t] + woacc[2][t] + woacc[3][t] + b2[0];
  }
}

extern "C" void kernel_launch(void* const* d_in, const int* in_sizes, int n_in,
                              void* d_out, int out_size, void* d_ws, size_t ws_size,
                              hipStream_t stream) {
  const int*   h_id  = (const int*)  d_in[0];
  const int*   r_id  = (const int*)  d_in[1];
  const int*   t_id  = (const int*)  d_in[2];
  const float* q     = (const float*)d_in[3];
  const float* ent   = (const float*)d_in[4];
  const float* rel   = (const float*)d_in[6];
  const float* topic = (const float*)d_in[7];
  const int*   mids  = (const int*)  d_in[8];
  const float* mwts  = (const float*)d_in[9];
  const float* ntx   = (const float*)d_in[10];
  const float* motif = (const float*)d_in[11];
  const float* W_nb  = (const float*)d_in[12];
  const float* b_nb  = (const float*)d_in[13];
  const float* W_pos = (const float*)d_in[14];
  const float* b_pos = (const float*)d_in[15];
  const float* W_str = (const float*)d_in[16];
  const float* b_str = (const float*)d_in[17];
  const float* W_g   = (const float*)d_in[18];
  const float* b_g   = (const float*)d_in[19];
  const float* W1    = (const float*)d_in[20];
  const float* b1    = (const float*)d_in[21];
  const float* W2    = (const float*)d_in[22];
  const float* b2    = (const float*)d_in[23];
  float* out = (float*)d_out;

  const int E  = in_sizes[0];
  const int NT = in_sizes[4] / EMB;   // 80000 text entities
  const int N  = in_sizes[7] / 2;     // 100000 total nodes

  float* ws    = (float*)d_ws;
  float* cnt_f = ws;
  float* cnt_r = ws + (size_t)N;
  float* a1f   = ws + (size_t)2*N;
  float* a1r   = ws + (size_t)4*N;
  float* a2f   = ws + (size_t)6*N;
  float* a2r   = ws + (size_t)8*N;
  float* pos   = ws + (size_t)10*N;             // N x 10
  float* gateq = ws + (size_t)20*N;             // [g0,g1,g2,pad, qpart(256)]
  u16*   WB    = (u16*)(ws + (size_t)20*N + 512);   // 11 chunks x 8192 u16
  u16*   WN    = WB + (size_t)11*8192;              // 8*32*64*8 = 131072 u16
  float* S     = (float*)(WN + 131072);             // 2000*256 f32
  u16*   TA    = (u16*)(S + (size_t)2000*256);      // (NT+1) x 256 bf16
  u16*   TB    = TA + (size_t)(NT+1)*256;

  hipMemsetAsync(d_ws, 0, (size_t)10 * N * sizeof(float), stream);

  int gE = (E + 255) / 256, gN = (N + 255) / 256;
  k_scatter1<<<gE, 256, 0, stream>>>(h_id, t_id, topic, cnt_f, cnt_r, a1f, a1r, E);
  k_div1    <<<gN, 256, 0, stream>>>(topic, cnt_f, cnt_r, a1f, a1r, pos, N);
  k_scatter2<<<gE, 256, 0, stream>>>(h_id, t_id, pos, a2f, a2r, E);
  k_div2    <<<gN, 256, 0, stream>>>(cnt_f, cnt_r, a2f, a2r, pos, N);
  k_gate    <<<1, 256, 0, stream>>>(q, W_g, b_g, W1, b1, gateq);
  k_wtrans  <<<108, 256, 0, stream>>>(W_pos, W_str, W1, W_nb, WB, WN);
  k_S       <<<2000, 256, 0, stream>>>(rel, W_str, S);
  k_node    <<<(NT + 64) / 64, 512, 0, stream>>>(ent, ntx, WN, TA, TB, NT);

  int gM = (E + 127) / 128;
  k_main<<<gM, 512, 0, stream>>>(h_id, r_id, t_id, mids, mwts, motif,
                                 b_nb, b_pos, b_str, W2, b2,
                                 pos, gateq, WB, S, TA, TB, out, E, NT);
}

// Round 8
// 404.029 us; speedup vs baseline: 1.7454x; 1.1556x over previous
//
#include <hip/hip_runtime.h>

#define EMB 256
typedef unsigned short u16;
typedef __attribute__((ext_vector_type(8))) short short8v;
typedef __attribute__((ext_vector_type(4))) short short4v;
typedef __attribute__((ext_vector_type(4))) float f32x4;

__device__ inline u16 f2bf(float x){
  union{float f; unsigned u;} c; c.f = x;
  unsigned r = c.u + 0x7FFFu + ((c.u>>16)&1u);
  return (u16)(r>>16);
}
__device__ inline float bf2f(u16 h){
  union{unsigned u; float f;} c; c.u = ((unsigned)h) << 16; return c.f;
}

// ---------------- DDE: counts + round-1 scatter fused ----------------
__global__ void k_scatter1(const int* __restrict__ h_id, const int* __restrict__ t_id,
                           const float* __restrict__ topic,
                           float* __restrict__ cnt_f, float* __restrict__ cnt_r,
                           float* __restrict__ accf, float* __restrict__ accr, int E) {
  int e = blockIdx.x * 256 + threadIdx.x;
  if (e >= E) return;
  int h = h_id[e], t = t_id[e];
  atomicAdd(&cnt_f[t], 1.0f);
  atomicAdd(&cnt_r[h], 1.0f);
  float a0 = topic[2*h+0], a1 = topic[2*h+1];
  if (a0 != 0.f) atomicAdd(&accf[2*t+0], a0);
  if (a1 != 0.f) atomicAdd(&accf[2*t+1], a1);
  float c0 = topic[2*t+0], c1 = topic[2*t+1];
  if (c0 != 0.f) atomicAdd(&accr[2*h+0], c0);
  if (c1 != 0.f) atomicAdd(&accr[2*h+1], c1);
}

// block 0: gate softmax + qpart; blocks 1..gN: div1
__global__ void k_div1_gate(const float* __restrict__ topic,
                            const float* __restrict__ cnt_f, const float* __restrict__ cnt_r,
                            const float* __restrict__ accf, const float* __restrict__ accr,
                            float* __restrict__ pos, int N,
                            const float* __restrict__ q, const float* __restrict__ Wg,
                            const float* __restrict__ bg, const float* __restrict__ W1,
                            const float* __restrict__ b1, float* __restrict__ gateq) {
  int t = threadIdx.x;
  if (blockIdx.x == 0) {
    __shared__ float qs[256];
    __shared__ float z[3];
    qs[t] = q[t];
    __syncthreads();
    if (t < 3) {
      float s = bg[t];
      for (int k = 0; k < 256; ++k) s += qs[k] * Wg[k*3 + t];
      z[t] = s;
    }
    __syncthreads();
    if (t == 0) {
      float m = fmaxf(z[0], fmaxf(z[1], z[2]));
      float e0 = expf(z[0]-m), e1 = expf(z[1]-m), e2 = expf(z[2]-m);
      float s = e0 + e1 + e2;
      gateq[0] = e0/s; gateq[1] = e1/s; gateq[2] = e2/s; gateq[3] = 0.f;
    }
    float a = b1[t];
    for (int k = 0; k < 256; ++k) a += qs[k] * W1[k*256 + t];
    gateq[4 + t] = a;
    return;
  }
  int n = (blockIdx.x - 1) * 256 + t;
  if (n >= N) return;
  float cf = fmaxf(cnt_f[n], 1.0f), cr = fmaxf(cnt_r[n], 1.0f);
  pos[10*n+0] = topic[2*n+0];
  pos[10*n+1] = topic[2*n+1];
  pos[10*n+2] = accf[2*n+0] / cf;
  pos[10*n+3] = accf[2*n+1] / cf;
  pos[10*n+6] = accr[2*n+0] / cr;
  pos[10*n+7] = accr[2*n+1] / cr;
}

__global__ void k_scatter2(const int* __restrict__ h_id, const int* __restrict__ t_id,
                           const float* __restrict__ pos,
                           float* __restrict__ accf, float* __restrict__ accr, int E) {
  int e = blockIdx.x * 256 + threadIdx.x;
  if (e >= E) return;
  int h = h_id[e], t = t_id[e];
  float a0 = pos[10*h+2], a1 = pos[10*h+3];
  if (a0 != 0.f) atomicAdd(&accf[2*t+0], a0);
  if (a1 != 0.f) atomicAdd(&accf[2*t+1], a1);
  float c0 = pos[10*t+6], c1 = pos[10*t+7];
  if (c0 != 0.f) atomicAdd(&accr[2*h+0], c0);
  if (c1 != 0.f) atomicAdd(&accr[2*h+1], c1);
}

__global__ void k_div2(const float* __restrict__ cnt_f, const float* __restrict__ cnt_r,
                       const float* __restrict__ accf, const float* __restrict__ accr,
                       float* __restrict__ pos, int N) {
  int n = blockIdx.x * 256 + threadIdx.x;
  if (n >= N) return;
  float cf = fmaxf(cnt_f[n], 1.0f), cr = fmaxf(cnt_r[n], 1.0f);
  pos[10*n+4] = accf[2*n+0] / cf;
  pos[10*n+5] = accf[2*n+1] / cf;
  pos[10*n+8] = accr[2*n+0] / cr;
  pos[10*n+9] = accr[2*n+1] / cr;
}

// ---------------- weight transforms ----------------
// WB A-frags (11 chunks of K=32): [0]=W_pos(20), [1,2]=W_str[256:320] (K=64), [3..10]=W1[256:512].
// WN B-frags for k_node (8 chunks x 32 col-tiles), cols 0..511 = [Wnb_top | Wnb_bot].
__global__ void k_wtrans(const float* __restrict__ Wpos, const float* __restrict__ Wstr,
                         const float* __restrict__ W1, const float* __restrict__ Wnb,
                         u16* __restrict__ WB, u16* __restrict__ WN) {
  int gid = blockIdx.x * 256 + threadIdx.x;
  if (gid < 11*1024) {
    int lane = gid & 63, ft = (gid >> 6) & 15, kt = gid >> 10;
    const float* src; int kbase, klim;
    if (kt == 0)      { src = Wpos;            kbase = 0;          klim = 20;  }
    else if (kt < 3)  { src = Wstr + 256*256;  kbase = (kt-1)*32;  klim = 64;  }
    else              { src = W1 + 256*256;    kbase = (kt-3)*32;  klim = 256; }
    int n  = ft*16 + (lane & 15);
    int k0 = kbase + (lane >> 4) * 8;
    short8v v;
    #pragma unroll
    for (int j = 0; j < 8; ++j) {
      int k = k0 + j;
      v[j] = (k < klim) ? (short)f2bf(src[(size_t)k*256 + n]) : (short)0;
    }
    *(short8v*)(WB + (size_t)gid * 8) = v;
  } else {
    int g2 = gid - 11*1024;
    if (g2 >= 8*32*64) return;
    int lane = g2 & 63, nt = (g2 >> 6) & 31, kc = g2 >> 11;
    int col = nt*16 + (lane & 15);
    int k0  = kc*32 + (lane >> 4) * 8;
    short8v v;
    #pragma unroll
    for (int j = 0; j < 8; ++j) {
      int k = k0 + j;
      float x = (col < 256) ? Wnb[(size_t)k*256 + col] : Wnb[(size_t)(256+k)*256 + (col-256)];
      v[j] = (short)f2bf(x);
    }
    *(short8v*)(WN + (size_t)g2 * 8) = v;
  }
}

// ---------------- node tables + S, fused ----------------
// blocks [0, nNodeBlk): TA[n]=h_e[n]@Wnb_top, TB[n]=h_e[n]@Wnb_bot (bf16).
// blocks [nNodeBlk, nNodeBlk+1000): S rows 2i, 2i+1 = rel @ W_str_top (f32).
__global__ __launch_bounds__(512) void k_node_S(const float* __restrict__ ent,
                                                const float* __restrict__ ntx,
                                                const u16* __restrict__ WN,
                                                u16* __restrict__ TA, u16* __restrict__ TB,
                                                int NT, int nNodeBlk,
                                                const float* __restrict__ rel,
                                                const float* __restrict__ Wstr,
                                                float* __restrict__ S) {
  const int t = threadIdx.x;
  if ((int)blockIdx.x >= nNodeBlk) {
    __shared__ float rs[2][256];
    int half = t >> 8, tc = t & 255;
    int r = (blockIdx.x - nNodeBlk) * 2 + half;
    rs[half][tc] = rel[(size_t)r*256 + tc];
    __syncthreads();
    float a = 0.f;
    for (int k = 0; k < 256; ++k) a = fmaf(rs[half][k], Wstr[(size_t)k*256 + tc], a);
    S[(size_t)r*256 + tc] = a;
    return;
  }
  __shared__ __align__(16) u16 AF[4*64*8];   // A chunk frags (4 KB)
  __shared__ __align__(16) u16 TT[64*512];   // output tile (64 KB)
  const int wv = t >> 6, l = t & 63;
  const int lr = l & 15, lg = l >> 4;
  const int nb0 = blockIdx.x * 64;

  const int mt = t >> 7, half = (t >> 6) & 1, l2 = t & 63;
  int snode = nb0 + mt*16 + (l2 & 15);
  const float* srow = (snode < NT) ? (ent + (size_t)snode * EMB) : ntx;

  f32x4 acc[4][4];
  #pragma unroll
  for (int m = 0; m < 4; ++m)
    #pragma unroll
    for (int n = 0; n < 4; ++n) acc[m][n] = (f32x4){0.f,0.f,0.f,0.f};

  for (int kc = 0; kc < 8; ++kc) {
    {
      int k = kc*32 + (l2 >> 4)*8 + half*4;
      float4 a4 = *(const float4*)(srow + k);
      short4v v;
      v[0]=(short)f2bf(a4.x); v[1]=(short)f2bf(a4.y);
      v[2]=(short)f2bf(a4.z); v[3]=(short)f2bf(a4.w);
      *(short4v*)&AF[((mt*64 + l2)*8 + half*4)] = v;
    }
    __syncthreads();
    short8v bn[4], af[4];
    #pragma unroll
    for (int n = 0; n < 4; ++n)
      bn[n] = *(const short8v*)&WN[((size_t)(kc*32 + wv*4 + n)*64 + l)*8];
    #pragma unroll
    for (int m = 0; m < 4; ++m)
      af[m] = *(const short8v*)&AF[(m*64 + l)*8];
    #pragma unroll
    for (int m = 0; m < 4; ++m)
      #pragma unroll
      for (int n = 0; n < 4; ++n)
        acc[m][n] = __builtin_amdgcn_mfma_f32_16x16x32_bf16(af[m], bn[n], acc[m][n], 0, 0, 0);
    __syncthreads();
  }
  #pragma unroll
  for (int m = 0; m < 4; ++m)
    #pragma unroll
    for (int n = 0; n < 4; ++n) {
      int col = wv*64 + n*16 + lr;
      #pragma unroll
      for (int r2 = 0; r2 < 4; ++r2)
        TT[(m*16 + lg*4 + r2)*512 + col] = f2bf(acc[m][n][r2]);
    }
  __syncthreads();
  #pragma unroll
  for (int p = 0; p < 8; ++p) {
    int idx = p*512 + t;
    int nrow = idx >> 6, grp = idx & 63, col = grp*8;
    int node = nb0 + nrow;
    if (node <= NT) {
      uint4 v = *(const uint4*)&TT[nrow*512 + col];
      u16* dst = (col < 256) ? (TA + (size_t)node*256 + col)
                             : (TB + (size_t)node*256 + (col-256));
      *(uint4*)dst = v;
    }
  }
}

// ---------------- main kernel: 128 edges/block, 8 waves (4Mw x 2Nw) ----------------
// __launch_bounds__(512, 4): 4 waves/EU -> <=128 regs incl. AGPR -> 2 blocks/CU.
__global__ __launch_bounds__(512, 4)
void k_main(
    const int* __restrict__ h_id, const int* __restrict__ r_id, const int* __restrict__ t_id,
    const int* __restrict__ mids, const float* __restrict__ mwts,
    const float* __restrict__ motif,
    const float* __restrict__ b_nb, const float* __restrict__ b_pos, const float* __restrict__ b_str,
    const float* __restrict__ W2, const float* __restrict__ b2,
    const float* __restrict__ pos, const float* __restrict__ gateq,
    const u16* __restrict__ WB, const float* __restrict__ S,
    const u16* __restrict__ TA, const u16* __restrict__ TB,
    float* __restrict__ out, int E, int NT)
{
  __shared__ __align__(16) u16 FT2[8*8*64*8];   // fused [k=256][edge=128] frag order (64 KB)
  __shared__ __align__(16) u16 XB[8*64*8];      // one staged B chunk (8 KB)
  __shared__ int ridsh[128];
  __shared__ float woacc[4][128];

  const int t  = threadIdx.x;
  const int wv = t >> 6, l = t & 63;
  const int Mw = wv >> 1, Nw = wv & 1;
  const int lr = l & 15, lg = l >> 4;
  const int be = blockIdx.x * 128;

  int eo = be + wv*16 + lr; if (eo >= E) eo = E - 1;
  const int hid = h_id[eo], tid = t_id[eo];
  if (t < 128) {
    int e = be + t; if (e >= E) e = E - 1;
    ridsh[t] = r_id[e];
  }

  const float g0 = gateq[0], g1 = gateq[1], g2 = gateq[2];

  f32x4 acc[4][4];
  auto zacc = [&]() {
    #pragma unroll
    for (int m = 0; m < 4; ++m)
      #pragma unroll
      for (int n = 0; n < 4; ++n) acc[m][n] = (f32x4){0.f,0.f,0.f,0.f};
  };

  auto mfma_chunk = [&](const u16* wc) {
    short8v af[4], bfr[4];
    #pragma unroll
    for (int m = 0; m < 4; ++m)
      af[m] = *(const short8v*)&wc[((Mw*4 + m)*64 + l)*8];
    #pragma unroll
    for (int n = 0; n < 4; ++n)
      bfr[n] = *(const short8v*)&XB[((Nw*4 + n)*64 + l)*8];
    #pragma unroll
    for (int m = 0; m < 4; ++m)
      #pragma unroll
      for (int n = 0; n < 4; ++n)
        acc[m][n] = __builtin_amdgcn_mfma_f32_16x16x32_bf16(af[m], bfr[n], acc[m][n], 0, 0, 0);
  };

  // ===== pos chunk stage =====
  {
    float vals[8];
    #pragma unroll
    for (int j = 0; j < 8; ++j) {
      int k = lg*8 + j;
      vals[j] = (k < 10) ? pos[(size_t)hid*10 + k]
              : (k < 20) ? pos[(size_t)tid*10 + (k - 10)] : 0.f;
    }
    short8v v;
    #pragma unroll
    for (int j = 0; j < 8; ++j) v[j] = (short)f2bf(vals[j]);
    *(short8v*)&XB[(wv*64 + l)*8] = v;
  }
  zacc();
  __syncthreads();
  mfma_chunk(WB);                                  // chunk 0 = W_pos
  {
    #pragma unroll
    for (int m = 0; m < 4; ++m) {
      int f0 = Mw*64 + m*16 + lg*4;
      float4 bs = *(const float4*)&b_pos[f0];
      int kc  = Mw*2 + ((m*4 + lg) >> 3);
      int lg2 = (m*2 + (lg >> 1)) & 3;
      #pragma unroll
      for (int n = 0; n < 4; ++n) {
        int nt = Nw*4 + n;
        int idx = ((kc*8 + nt)*64 + lg2*16 + lr)*8 + (lg & 1)*4;
        short4v w;
        w[0] = (short)f2bf(g1 * fmaxf(acc[m][n][0] + bs.x, 0.f));
        w[1] = (short)f2bf(g1 * fmaxf(acc[m][n][1] + bs.y, 0.f));
        w[2] = (short)f2bf(g1 * fmaxf(acc[m][n][2] + bs.z, 0.f));
        w[3] = (short)f2bf(g1 * fmaxf(acc[m][n][3] + bs.w, 0.f));
        *(short4v*)&FT2[idx] = w;
      }
    }
  }
  zacc();
  __syncthreads();

  // ===== motif: 2 chunks (K=64) =====
  int mid8[8]; float mw8[8];
  #pragma unroll
  for (int j = 0; j < 8; ++j) {
    mid8[j] = mids[(size_t)eo*8 + j];
    mw8[j]  = mwts[(size_t)eo*8 + j];
  }
  auto stage_motif = [&](int cc) {
    int d0 = cc*32 + lg*8;
    float s[8] = {0,0,0,0,0,0,0,0};
    #pragma unroll
    for (int jt = 0; jt < 8; ++jt) {
      if (mid8[jt] != 0) {
        const float* mr = motif + (size_t)mid8[jt]*64 + d0;
        float wt = mw8[jt];
        #pragma unroll
        for (int i = 0; i < 8; ++i) s[i] = fmaf(mr[i], wt, s[i]);
      }
    }
    short8v v;
    #pragma unroll
    for (int i = 0; i < 8; ++i) v[i] = (short)f2bf(s[i]);
    *(short8v*)&XB[(wv*64 + l)*8] = v;
  };
  stage_motif(0);
  __syncthreads();
  mfma_chunk(WB + 1*8192);
  __syncthreads();
  stage_motif(1);
  __syncthreads();
  mfma_chunk(WB + 2*8192);
  // combine struct: S gather + b_str, RMW FT2
  {
    #pragma unroll
    for (int m = 0; m < 4; ++m) {
      int f0 = Mw*64 + m*16 + lg*4;
      float4 bs = *(const float4*)&b_str[f0];
      int kc  = Mw*2 + ((m*4 + lg) >> 3);
      int lg2 = (m*2 + (lg >> 1)) & 3;
      #pragma unroll
      for (int n = 0; n < 4; ++n) {
        int nt = Nw*4 + n;
        int r = ridsh[nt*16 + lr];
        float4 sv = *(const float4*)&S[(size_t)r*256 + f0];
        int idx = ((kc*8 + nt)*64 + lg2*16 + lr)*8 + (lg & 1)*4;
        short4v o = *(const short4v*)&FT2[idx];
        short4v w;
        w[0] = (short)f2bf(bf2f((u16)o[0]) + g2 * fmaxf(acc[m][n][0] + sv.x + bs.x, 0.f));
        w[1] = (short)f2bf(bf2f((u16)o[1]) + g2 * fmaxf(acc[m][n][1] + sv.y + bs.y, 0.f));
        w[2] = (short)f2bf(bf2f((u16)o[2]) + g2 * fmaxf(acc[m][n][2] + sv.z + bs.z, 0.f));
        w[3] = (short)f2bf(bf2f((u16)o[3]) + g2 * fmaxf(acc[m][n][3] + sv.w + bs.w, 0.f));
        *(short4v*)&FT2[idx] = w;
      }
    }
  }
  __syncthreads();

  // ===== nb channel: gather TA[h]/TB[t], RMW own FT2 slots (2-chunk batches) =====
  {
    const u16* pa = TA + (size_t)((hid < NT) ? hid : NT) * 256;
    const u16* pb = TB + (size_t)((tid < NT) ? tid : NT) * 256;
    #pragma unroll
    for (int kk = 0; kk < 8; kk += 2) {
      short8v la0 = *(const short8v*)(pa + kk*32 + lg*8);
      short8v lb0 = *(const short8v*)(pb + kk*32 + lg*8);
      short8v la1 = *(const short8v*)(pa + (kk+1)*32 + lg*8);
      short8v lb1 = *(const short8v*)(pb + (kk+1)*32 + lg*8);
      #pragma unroll
      for (int c2 = 0; c2 < 2; ++c2) {
        int kc = kk + c2;
        short8v la = c2 ? la1 : la0;
        short8v lb = c2 ? lb1 : lb0;
        int k0 = kc*32 + lg*8;
        float4 bb0 = *(const float4*)&b_nb[k0];
        float4 bb1 = *(const float4*)&b_nb[k0 + 4];
        u16* slot = &FT2[((kc*8 + wv)*64 + l)*8];
        short8v o = *(const short8v*)slot;
        short8v w;
        w[0] = (short)f2bf(bf2f((u16)o[0]) + g0*fmaxf(bf2f((u16)la[0])+bf2f((u16)lb[0])+bb0.x, 0.f));
        w[1] = (short)f2bf(bf2f((u16)o[1]) + g0*fmaxf(bf2f((u16)la[1])+bf2f((u16)lb[1])+bb0.y, 0.f));
        w[2] = (short)f2bf(bf2f((u16)o[2]) + g0*fmaxf(bf2f((u16)la[2])+bf2f((u16)lb[2])+bb0.z, 0.f));
        w[3] = (short)f2bf(bf2f((u16)o[3]) + g0*fmaxf(bf2f((u16)la[3])+bf2f((u16)lb[3])+bb0.w, 0.f));
        w[4] = (short)f2bf(bf2f((u16)o[4]) + g0*fmaxf(bf2f((u16)la[4])+bf2f((u16)lb[4])+bb1.x, 0.f));
        w[5] = (short)f2bf(bf2f((u16)o[5]) + g0*fmaxf(bf2f((u16)la[5])+bf2f((u16)lb[5])+bb1.y, 0.f));
        w[6] = (short)f2bf(bf2f((u16)o[6]) + g0*fmaxf(bf2f((u16)la[6])+bf2f((u16)lb[6])+bb1.z, 0.f));
        w[7] = (short)f2bf(bf2f((u16)o[7]) + g0*fmaxf(bf2f((u16)la[7])+bf2f((u16)lb[7])+bb1.w, 0.f));
        *(short8v*)slot = w;
      }
    }
  }

  // ===== layer 1: acc init = qpart, B = FT2, A = W1 chunks 3..10 =====
  #pragma unroll
  for (int m = 0; m < 4; ++m) {
    int f0 = Mw*64 + m*16 + lg*4;
    f32x4 qv = { gateq[4+f0], gateq[5+f0], gateq[6+f0], gateq[7+f0] };
    #pragma unroll
    for (int n = 0; n < 4; ++n) acc[m][n] = qv;
  }
  __syncthreads();
  for (int c2 = 0; c2 < 8; ++c2) {
    const u16* wc = WB + (size_t)(3 + c2) * 8192;
    short8v af[4], bfr[4];
    #pragma unroll
    for (int m = 0; m < 4; ++m)
      af[m] = *(const short8v*)&wc[((Mw*4 + m)*64 + l)*8];
    #pragma unroll
    for (int n = 0; n < 4; ++n)
      bfr[n] = *(const short8v*)&FT2[((c2*8 + Nw*4 + n)*64 + l)*8];
    #pragma unroll
    for (int m = 0; m < 4; ++m)
      #pragma unroll
      for (int n = 0; n < 4; ++n)
        acc[m][n] = __builtin_amdgcn_mfma_f32_16x16x32_bf16(af[m], bfr[n], acc[m][n], 0, 0, 0);
  }

  // ===== layer 2 =====
  {
    float w2v[4][4];
    #pragma unroll
    for (int m = 0; m < 4; ++m) {
      int f0 = Mw*64 + m*16 + lg*4;
      #pragma unroll
      for (int r2 = 0; r2 < 4; ++r2) w2v[m][r2] = W2[f0 + r2];
    }
    #pragma unroll
    for (int n = 0; n < 4; ++n) {
      float p = 0.f;
      #pragma unroll
      for (int m = 0; m < 4; ++m)
        #pragma unroll
        for (int r2 = 0; r2 < 4; ++r2)
          p = fmaf(fmaxf(acc[m][n][r2], 0.f), w2v[m][r2], p);
      p += __shfl_xor(p, 16);
      p += __shfl_xor(p, 32);
      if (lg == 0) woacc[Mw][Nw*64 + n*16 + lr] = p;
    }
  }
  __syncthreads();
  if (t < 128) {
    int e = be + t;
    if (e < E)
      out[e] = woacc[0][t] + woacc[1][t] + woacc[2][t] + woacc[3][t] + b2[0];
  }
}

extern "C" void kernel_launch(void* const* d_in, const int* in_sizes, int n_in,
                              void* d_out, int out_size, void* d_ws, size_t ws_size,
                              hipStream_t stream) {
  const int*   h_id  = (const int*)  d_in[0];
  const int*   r_id  = (const int*)  d_in[1];
  const int*   t_id  = (const int*)  d_in[2];
  const float* q     = (const float*)d_in[3];
  const float* ent   = (const float*)d_in[4];
  const float* rel   = (const float*)d_in[6];
  const float* topic = (const float*)d_in[7];
  const int*   mids  = (const int*)  d_in[8];
  const float* mwts  = (const float*)d_in[9];
  const float* ntx   = (const float*)d_in[10];
  const float* motif = (const float*)d_in[11];
  const float* W_nb  = (const float*)d_in[12];
  const float* b_nb  = (const float*)d_in[13];
  const float* W_pos = (const float*)d_in[14];
  const float* b_pos = (const float*)d_in[15];
  const float* W_str = (const float*)d_in[16];
  const float* b_str = (const float*)d_in[17];
  const float* W_g   = (const float*)d_in[18];
  const float* b_g   = (const float*)d_in[19];
  const float* W1    = (const float*)d_in[20];
  const float* b1    = (const float*)d_in[21];
  const float* W2    = (const float*)d_in[22];
  const float* b2    = (const float*)d_in[23];
  float* out = (float*)d_out;

  const int E  = in_sizes[0];
  const int NT = in_sizes[4] / EMB;   // 80000 text entities
  const int N  = in_sizes[7] / 2;     // 100000 total nodes

  float* ws    = (float*)d_ws;
  float* cnt_f = ws;
  float* cnt_r = ws + (size_t)N;
  float* a1f   = ws + (size_t)2*N;
  float* a1r   = ws + (size_t)4*N;
  float* a2f   = ws + (size_t)6*N;
  float* a2r   = ws + (size_t)8*N;
  float* pos   = ws + (size_t)10*N;             // N x 10
  float* gateq = ws + (size_t)20*N;             // [g0,g1,g2,pad, qpart(256)]
  u16*   WB    = (u16*)(ws + (size_t)20*N + 512);   // 11 chunks x 8192 u16
  u16*   WN    = WB + (size_t)11*8192;              // 8*32*64*8 = 131072 u16
  float* S     = (float*)(WN + 131072);             // 2000*256 f32
  u16*   TA    = (u16*)(S + (size_t)2000*256);      // (NT+1) x 256 bf16
  u16*   TB    = TA + (size_t)(NT+1)*256;

  hipMemsetAsync(d_ws, 0, (size_t)10 * N * sizeof(float), stream);

  int gE = (E + 255) / 256, gN = (N + 255) / 256;
  int nNodeBlk = (NT + 64) / 64;
  k_scatter1 <<<gE, 256, 0, stream>>>(h_id, t_id, topic, cnt_f, cnt_r, a1f, a1r, E);
  k_div1_gate<<<gN + 1, 256, 0, stream>>>(topic, cnt_f, cnt_r, a1f, a1r, pos, N,
                                          q, W_g, b_g, W1, b1, gateq);
  k_scatter2 <<<gE, 256, 0, stream>>>(h_id, t_id, pos, a2f, a2r, E);
  k_div2     <<<gN, 256, 0, stream>>>(cnt_f, cnt_r, a2f, a2r, pos, N);
  k_wtrans   <<<108, 256, 0, stream>>>(W_pos, W_str, W1, W_nb, WB, WN);
  k_node_S   <<<nNodeBlk + 1000, 512, 0, stream>>>(ent, ntx, WN, TA, TB, NT, nNodeBlk,
                                                   rel, W_str, S);

  int gM = (E + 127) / 128;
  k_main<<<gM, 512, 0, stream>>>(h_id, r_id, t_id, mids, mwts, motif,
                                 b_nb, b_pos, b_str, W2, b2,
                                 pos, gateq, WB, S, TA, TB, out, E, NT);
}

// Round 9
// 386.907 us; speedup vs baseline: 1.8226x; 1.0443x over previous
//
#include <hip/hip_runtime.h>

#define EMB 256
typedef unsigned short u16;
typedef __attribute__((ext_vector_type(8))) short short8v;
typedef __attribute__((ext_vector_type(4))) short short4v;
typedef __attribute__((ext_vector_type(4))) float f32x4;

__device__ inline u16 f2bf(float x){
  union{float f; unsigned u;} c; c.f = x;
  unsigned r = c.u + 0x7FFFu + ((c.u>>16)&1u);
  return (u16)(r>>16);
}
__device__ inline float bf2f(u16 h){
  union{unsigned u; float f;} c; c.u = ((unsigned)h) << 16; return c.f;
}

// ---------------- DDE: counts + round-1 scatter fused ----------------
__global__ void k_scatter1(const int* __restrict__ h_id, const int* __restrict__ t_id,
                           const float* __restrict__ topic,
                           float* __restrict__ cnt_f, float* __restrict__ cnt_r,
                           float* __restrict__ accf, float* __restrict__ accr, int E) {
  int e = blockIdx.x * 256 + threadIdx.x;
  if (e >= E) return;
  int h = h_id[e], t = t_id[e];
  atomicAdd(&cnt_f[t], 1.0f);
  atomicAdd(&cnt_r[h], 1.0f);
  float a0 = topic[2*h+0], a1 = topic[2*h+1];
  if (a0 != 0.f) atomicAdd(&accf[2*t+0], a0);
  if (a1 != 0.f) atomicAdd(&accf[2*t+1], a1);
  float c0 = topic[2*t+0], c1 = topic[2*t+1];
  if (c0 != 0.f) atomicAdd(&accr[2*h+0], c0);
  if (c1 != 0.f) atomicAdd(&accr[2*h+1], c1);
}

// block 0: gate softmax + qpart; blocks 1..gN: div1
__global__ void k_div1_gate(const float* __restrict__ topic,
                            const float* __restrict__ cnt_f, const float* __restrict__ cnt_r,
                            const float* __restrict__ accf, const float* __restrict__ accr,
                            float* __restrict__ pos, int N,
                            const float* __restrict__ q, const float* __restrict__ Wg,
                            const float* __restrict__ bg, const float* __restrict__ W1,
                            const float* __restrict__ b1, float* __restrict__ gateq) {
  int t = threadIdx.x;
  if (blockIdx.x == 0) {
    __shared__ float qs[256];
    __shared__ float z[3];
    qs[t] = q[t];
    __syncthreads();
    if (t < 3) {
      float s = bg[t];
      for (int k = 0; k < 256; ++k) s += qs[k] * Wg[k*3 + t];
      z[t] = s;
    }
    __syncthreads();
    if (t == 0) {
      float m = fmaxf(z[0], fmaxf(z[1], z[2]));
      float e0 = expf(z[0]-m), e1 = expf(z[1]-m), e2 = expf(z[2]-m);
      float s = e0 + e1 + e2;
      gateq[0] = e0/s; gateq[1] = e1/s; gateq[2] = e2/s; gateq[3] = 0.f;
    }
    float a = b1[t];
    for (int k = 0; k < 256; ++k) a += qs[k] * W1[k*256 + t];
    gateq[4 + t] = a;
    return;
  }
  int n = (blockIdx.x - 1) * 256 + t;
  if (n >= N) return;
  float cf = fmaxf(cnt_f[n], 1.0f), cr = fmaxf(cnt_r[n], 1.0f);
  pos[10*n+0] = topic[2*n+0];
  pos[10*n+1] = topic[2*n+1];
  pos[10*n+2] = accf[2*n+0] / cf;
  pos[10*n+3] = accf[2*n+1] / cf;
  pos[10*n+6] = accr[2*n+0] / cr;
  pos[10*n+7] = accr[2*n+1] / cr;
}

__global__ void k_scatter2(const int* __restrict__ h_id, const int* __restrict__ t_id,
                           const float* __restrict__ pos,
                           float* __restrict__ accf, float* __restrict__ accr, int E) {
  int e = blockIdx.x * 256 + threadIdx.x;
  if (e >= E) return;
  int h = h_id[e], t = t_id[e];
  float a0 = pos[10*h+2], a1 = pos[10*h+3];
  if (a0 != 0.f) atomicAdd(&accf[2*t+0], a0);
  if (a1 != 0.f) atomicAdd(&accf[2*t+1], a1);
  float c0 = pos[10*t+6], c1 = pos[10*t+7];
  if (c0 != 0.f) atomicAdd(&accr[2*h+0], c0);
  if (c1 != 0.f) atomicAdd(&accr[2*h+1], c1);
}

__global__ void k_div2(const float* __restrict__ cnt_f, const float* __restrict__ cnt_r,
                       const float* __restrict__ accf, const float* __restrict__ accr,
                       float* __restrict__ pos, int N) {
  int n = blockIdx.x * 256 + threadIdx.x;
  if (n >= N) return;
  float cf = fmaxf(cnt_f[n], 1.0f), cr = fmaxf(cnt_r[n], 1.0f);
  pos[10*n+4] = accf[2*n+0] / cf;
  pos[10*n+5] = accf[2*n+1] / cf;
  pos[10*n+8] = accr[2*n+0] / cr;
  pos[10*n+9] = accr[2*n+1] / cr;
}

// ---------------- weight transforms (gate-folded) ----------------
// WB A-frags (11 chunks of K=32): [0]=g1*W_pos(20) with row20=g1*b_pos (bias row),
// [1,2]=g2*W_str[256:320] (K=64), [3..10]=W1[256:512] (unscaled).
// WN B-frags for k_node (8 chunks x 32 col-tiles), cols 0..511 = [Wnb_top | Wnb_bot].
__global__ void k_wtrans(const float* __restrict__ Wpos, const float* __restrict__ Wstr,
                         const float* __restrict__ W1, const float* __restrict__ Wnb,
                         const float* __restrict__ bpos, const float* __restrict__ gateq,
                         u16* __restrict__ WB, u16* __restrict__ WN) {
  int gid = blockIdx.x * 256 + threadIdx.x;
  if (gid < 11*1024) {
    int lane = gid & 63, ft = (gid >> 6) & 15, kt = gid >> 10;
    int n  = ft*16 + (lane & 15);
    int k0 = (lane >> 4) * 8;
    short8v v;
    if (kt == 0) {
      float g1 = gateq[1];
      #pragma unroll
      for (int j = 0; j < 8; ++j) {
        int k = k0 + j;
        float x = (k < 20) ? g1 * Wpos[(size_t)k*256 + n]
                : (k == 20) ? g1 * bpos[n] : 0.f;
        v[j] = (short)f2bf(x);
      }
    } else if (kt < 3) {
      float g2 = gateq[2];
      int kbase = (kt-1)*32;
      #pragma unroll
      for (int j = 0; j < 8; ++j)
        v[j] = (short)f2bf(g2 * Wstr[(size_t)(256 + kbase + k0 + j)*256 + n]);
    } else {
      int kbase = (kt-3)*32;
      #pragma unroll
      for (int j = 0; j < 8; ++j)
        v[j] = (short)f2bf(W1[(size_t)(256 + kbase + k0 + j)*256 + n]);
    }
    *(short8v*)(WB + (size_t)gid * 8) = v;
  } else {
    int g2i = gid - 11*1024;
    if (g2i >= 8*32*64) return;
    int lane = g2i & 63, nt = (g2i >> 6) & 31, kc = g2i >> 11;
    int col = nt*16 + (lane & 15);
    int k0  = kc*32 + (lane >> 4) * 8;
    short8v v;
    #pragma unroll
    for (int j = 0; j < 8; ++j) {
      int k = k0 + j;
      float x = (col < 256) ? Wnb[(size_t)k*256 + col] : Wnb[(size_t)(256+k)*256 + (col-256)];
      v[j] = (short)f2bf(x);
    }
    *(short8v*)(WN + (size_t)g2i * 8) = v;
  }
}

// ---------------- node tables + S, fused (gate/bias-folded) ----------------
// blocks [0, nNodeBlk): TA[n]=g0*(h_e[n]@Wnb_top + b_nb), TB[n]=g0*(h_e[n]@Wnb_bot) (bf16).
// blocks [nNodeBlk, +1000): S rows = g2*(rel @ W_str_top + b_str) (f32).
__global__ __launch_bounds__(512) void k_node_S(const float* __restrict__ ent,
                                                const float* __restrict__ ntx,
                                                const u16* __restrict__ WN,
                                                u16* __restrict__ TA, u16* __restrict__ TB,
                                                int NT, int nNodeBlk,
                                                const float* __restrict__ rel,
                                                const float* __restrict__ Wstr,
                                                const float* __restrict__ b_nb,
                                                const float* __restrict__ b_str,
                                                const float* __restrict__ gateq,
                                                float* __restrict__ S) {
  const int t = threadIdx.x;
  if ((int)blockIdx.x >= nNodeBlk) {
    __shared__ float rs[2][256];
    int half = t >> 8, tc = t & 255;
    int r = (blockIdx.x - nNodeBlk) * 2 + half;
    rs[half][tc] = rel[(size_t)r*256 + tc];
    __syncthreads();
    float a = 0.f;
    for (int k = 0; k < 256; ++k) a = fmaf(rs[half][k], Wstr[(size_t)k*256 + tc], a);
    S[(size_t)r*256 + tc] = gateq[2] * (a + b_str[tc]);
    return;
  }
  __shared__ __align__(16) u16 AF[4*64*8];
  __shared__ __align__(16) u16 TT[64*512];
  const int wv = t >> 6, l = t & 63;
  const int lr = l & 15, lg = l >> 4;
  const int nb0 = blockIdx.x * 64;
  const float g0 = gateq[0];

  const int mt = t >> 7, half = (t >> 6) & 1, l2 = t & 63;
  int snode = nb0 + mt*16 + (l2 & 15);
  const float* srow = (snode < NT) ? (ent + (size_t)snode * EMB) : ntx;

  f32x4 acc[4][4];
  #pragma unroll
  for (int m = 0; m < 4; ++m)
    #pragma unroll
    for (int n = 0; n < 4; ++n) acc[m][n] = (f32x4){0.f,0.f,0.f,0.f};

  for (int kc = 0; kc < 8; ++kc) {
    {
      int k = kc*32 + (l2 >> 4)*8 + half*4;
      float4 a4 = *(const float4*)(srow + k);
      short4v v;
      v[0]=(short)f2bf(a4.x); v[1]=(short)f2bf(a4.y);
      v[2]=(short)f2bf(a4.z); v[3]=(short)f2bf(a4.w);
      *(short4v*)&AF[((mt*64 + l2)*8 + half*4)] = v;
    }
    __syncthreads();
    short8v bn[4], af[4];
    #pragma unroll
    for (int n = 0; n < 4; ++n)
      bn[n] = *(const short8v*)&WN[((size_t)(kc*32 + wv*4 + n)*64 + l)*8];
    #pragma unroll
    for (int m = 0; m < 4; ++m)
      af[m] = *(const short8v*)&AF[(m*64 + l)*8];
    #pragma unroll
    for (int m = 0; m < 4; ++m)
      #pragma unroll
      for (int n = 0; n < 4; ++n)
        acc[m][n] = __builtin_amdgcn_mfma_f32_16x16x32_bf16(af[m], bn[n], acc[m][n], 0, 0, 0);
    __syncthreads();
  }
  #pragma unroll
  for (int m = 0; m < 4; ++m)
    #pragma unroll
    for (int n = 0; n < 4; ++n) {
      int col = wv*64 + n*16 + lr;
      float bias = (col < 256) ? b_nb[col] : 0.f;
      #pragma unroll
      for (int r2 = 0; r2 < 4; ++r2)
        TT[(m*16 + lg*4 + r2)*512 + col] = f2bf(g0 * (acc[m][n][r2] + bias));
    }
  __syncthreads();
  #pragma unroll
  for (int p = 0; p < 8; ++p) {
    int idx = p*512 + t;
    int nrow = idx >> 6, grp = idx & 63, col = grp*8;
    int node = nb0 + nrow;
    if (node <= NT) {
      uint4 v = *(const uint4*)&TT[nrow*512 + col];
      u16* dst = (col < 256) ? (TA + (size_t)node*256 + col)
                             : (TB + (size_t)node*256 + (col-256));
      *(uint4*)dst = v;
    }
  }
}

// ---------------- main kernel: 128 edges/block, 8 waves (4Mw x 2Nw) ----------------
__global__ __launch_bounds__(512, 4)
void k_main(
    const int* __restrict__ h_id, const int* __restrict__ r_id, const int* __restrict__ t_id,
    const int* __restrict__ mids, const float* __restrict__ mwts,
    const float* __restrict__ motif,
    const float* __restrict__ W2, const float* __restrict__ b2,
    const float* __restrict__ pos, const float* __restrict__ gateq,
    const u16* __restrict__ WB, const float* __restrict__ S,
    const u16* __restrict__ TA, const u16* __restrict__ TB,
    float* __restrict__ out, int E, int NT)
{
  __shared__ __align__(16) u16 FT2[8*8*64*8];   // fused [k=256][edge=128] frag order (64 KB)
  __shared__ __align__(16) u16 XB[8*64*8];      // one staged B chunk (8 KB)
  __shared__ int ridsh[128];
  __shared__ float woacc[4][128];

  const int t  = threadIdx.x;
  const int wv = t >> 6, l = t & 63;
  const int Mw = wv >> 1, Nw = wv & 1;
  const int lr = l & 15, lg = l >> 4;
  const int be = blockIdx.x * 128;

  int eo = be + wv*16 + lr; if (eo >= E) eo = E - 1;
  const int hid = h_id[eo], tid = t_id[eo];
  if (t < 128) {
    int e = be + t; if (e >= E) e = E - 1;
    ridsh[t] = r_id[e];
  }

  // motif ids/weights (vectorized, 32B-aligned)
  int4   mi0 = *(const int4*)  (mids + (size_t)eo*8);
  int4   mi1 = *(const int4*)  (mids + (size_t)eo*8 + 4);
  float4 mw0 = *(const float4*)(mwts + (size_t)eo*8);
  float4 mw1 = *(const float4*)(mwts + (size_t)eo*8 + 4);

  // ===== issue TA gathers async -> FT2 (dst = kc*8192 + wv*1024 + lane*16 bytes) =====
  {
    const int hc = (hid < NT) ? hid : NT;
    const u16* paw = TA + (size_t)hc*256 + lg*8;
    #pragma unroll
    for (int kc = 0; kc < 8; ++kc)
      __builtin_amdgcn_global_load_lds(
        (const __attribute__((address_space(1))) unsigned int*)(paw + kc*32),
        (__attribute__((address_space(3))) unsigned int*)&FT2[(size_t)kc*4096 + wv*512],
        16, 0, 0);
  }

  // ===== stage pos chunk -> XB (float2 pairs; k==20 -> 1.0 bias row) =====
  {
    float vals[8];
    #pragma unroll
    for (int jp = 0; jp < 4; ++jp) {
      int k2 = lg*8 + jp*2;
      float2 f2;
      if (k2 < 10)       f2 = *(const float2*)&pos[(size_t)hid*10 + k2];
      else if (k2 < 20)  f2 = *(const float2*)&pos[(size_t)tid*10 + (k2 - 10)];
      else if (k2 == 20) f2 = make_float2(1.f, 0.f);
      else               f2 = make_float2(0.f, 0.f);
      vals[jp*2] = f2.x; vals[jp*2+1] = f2.y;
    }
    short8v v;
    #pragma unroll
    for (int j = 0; j < 8; ++j) v[j] = (short)f2bf(vals[j]);
    *(short8v*)&XB[(wv*64 + l)*8] = v;
  }

  // ===== nb channel: TB via regs (2-ahead), TA from LDS; write FT2 = relu =====
  {
    const int tc2 = (tid < NT) ? tid : NT;
    const u16* pbw = TB + (size_t)tc2*256 + lg*8;
    short8v tb0 = *(const short8v*)(pbw);
    short8v tb1 = *(const short8v*)(pbw + 32);
    asm volatile("s_waitcnt vmcnt(0)" ::: "memory");
    __builtin_amdgcn_sched_barrier(0);
    #pragma unroll
    for (int kk = 0; kk < 8; kk += 2) {
      short8v nba = tb0, nbb = tb1;
      if (kk < 6) {
        tb0 = *(const short8v*)(pbw + (kk+2)*32);
        tb1 = *(const short8v*)(pbw + (kk+3)*32);
      }
      #pragma unroll
      for (int c2 = 0; c2 < 2; ++c2) {
        short8v nb = c2 ? nbb : nba;
        u16* slot = &FT2[(size_t)((kk+c2)*8 + wv)*512 + l*8];
        short8v o = *(const short8v*)slot;
        short8v w;
        #pragma unroll
        for (int j = 0; j < 8; ++j)
          w[j] = (short)f2bf(fmaxf(bf2f((u16)o[j]) + bf2f((u16)nb[j]), 0.f));
        *(short8v*)slot = w;
      }
    }
  }

  f32x4 acc[4][4];
  auto zacc = [&]() {
    #pragma unroll
    for (int m = 0; m < 4; ++m)
      #pragma unroll
      for (int n = 0; n < 4; ++n) acc[m][n] = (f32x4){0.f,0.f,0.f,0.f};
  };
  auto mfma_chunk = [&](const u16* wc) {
    short8v af[4], bfr[4];
    #pragma unroll
    for (int m = 0; m < 4; ++m)
      af[m] = *(const short8v*)&wc[((Mw*4 + m)*64 + l)*8];
    #pragma unroll
    for (int n = 0; n < 4; ++n)
      bfr[n] = *(const short8v*)&XB[((Nw*4 + n)*64 + l)*8];
    #pragma unroll
    for (int m = 0; m < 4; ++m)
      #pragma unroll
      for (int n = 0; n < 4; ++n)
        acc[m][n] = __builtin_amdgcn_mfma_f32_16x16x32_bf16(af[m], bfr[n], acc[m][n], 0, 0, 0);
  };

  zacc();
  __syncthreads();                 // FT2 nb writes + XB pos stage visible

  // ===== pos: MFMA + RMW combine (acc has g1*W_pos and bias row folded) =====
  mfma_chunk(WB);
  {
    #pragma unroll
    for (int m = 0; m < 4; ++m) {
      int kc  = Mw*2 + ((m*4 + lg) >> 3);
      int lg2 = (m*2 + (lg >> 1)) & 3;
      #pragma unroll
      for (int n = 0; n < 4; ++n) {
        int nt = Nw*4 + n;
        int idx = ((kc*8 + nt)*64 + lg2*16 + lr)*8 + (lg & 1)*4;
        short4v o = *(const short4v*)&FT2[idx];
        short4v w;
        w[0] = (short)f2bf(bf2f((u16)o[0]) + fmaxf(acc[m][n][0], 0.f));
        w[1] = (short)f2bf(bf2f((u16)o[1]) + fmaxf(acc[m][n][1], 0.f));
        w[2] = (short)f2bf(bf2f((u16)o[2]) + fmaxf(acc[m][n][2], 0.f));
        w[3] = (short)f2bf(bf2f((u16)o[3]) + fmaxf(acc[m][n][3], 0.f));
        *(short4v*)&FT2[idx] = w;
      }
    }
  }
  zacc();
  __syncthreads();                 // XB free for motif

  // ===== motif: 2 chunks (K=64), float4 gathers =====
  auto stage_motif = [&](int cc) {
    int d0 = cc*32 + lg*8;
    int   idv[8] = {mi0.x,mi0.y,mi0.z,mi0.w,mi1.x,mi1.y,mi1.z,mi1.w};
    float wtv[8] = {mw0.x,mw0.y,mw0.z,mw0.w,mw1.x,mw1.y,mw1.z,mw1.w};
    float s[8] = {0,0,0,0,0,0,0,0};
    #pragma unroll
    for (int jt = 0; jt < 8; ++jt) {
      if (idv[jt] != 0) {
        const float4* mp = (const float4*)(motif + (size_t)idv[jt]*64 + d0);
        float4 a = mp[0], b = mp[1];
        float wt = wtv[jt];
        s[0] = fmaf(a.x, wt, s[0]); s[1] = fmaf(a.y, wt, s[1]);
        s[2] = fmaf(a.z, wt, s[2]); s[3] = fmaf(a.w, wt, s[3]);
        s[4] = fmaf(b.x, wt, s[4]); s[5] = fmaf(b.y, wt, s[5]);
        s[6] = fmaf(b.z, wt, s[6]); s[7] = fmaf(b.w, wt, s[7]);
      }
    }
    short8v v;
    #pragma unroll
    for (int i = 0; i < 8; ++i) v[i] = (short)f2bf(s[i]);
    *(short8v*)&XB[(wv*64 + l)*8] = v;
  };
  stage_motif(0);
  __syncthreads();
  mfma_chunk(WB + 1*8192);
  __syncthreads();
  stage_motif(1);
  __syncthreads();
  mfma_chunk(WB + 2*8192);
  // combine struct: S already g2*(rel@Wstr+b_str); acc = g2*motif part
  {
    #pragma unroll
    for (int m = 0; m < 4; ++m) {
      int f0 = Mw*64 + m*16 + lg*4;
      int kc  = Mw*2 + ((m*4 + lg) >> 3);
      int lg2 = (m*2 + (lg >> 1)) & 3;
      #pragma unroll
      for (int n = 0; n < 4; ++n) {
        int nt = Nw*4 + n;
        int r = ridsh[nt*16 + lr];
        float4 sv = *(const float4*)&S[(size_t)r*256 + f0];
        int idx = ((kc*8 + nt)*64 + lg2*16 + lr)*8 + (lg & 1)*4;
        short4v o = *(const short4v*)&FT2[idx];
        short4v w;
        w[0] = (short)f2bf(bf2f((u16)o[0]) + fmaxf(acc[m][n][0] + sv.x, 0.f));
        w[1] = (short)f2bf(bf2f((u16)o[1]) + fmaxf(acc[m][n][1] + sv.y, 0.f));
        w[2] = (short)f2bf(bf2f((u16)o[2]) + fmaxf(acc[m][n][2] + sv.z, 0.f));
        w[3] = (short)f2bf(bf2f((u16)o[3]) + fmaxf(acc[m][n][3] + sv.w, 0.f));
        *(short4v*)&FT2[idx] = w;
      }
    }
  }

  // ===== layer 1: acc init = qpart, B = FT2, A = W1 chunks 3..10 =====
  #pragma unroll
  for (int m = 0; m < 4; ++m) {
    int f0 = Mw*64 + m*16 + lg*4;
    f32x4 qv = { gateq[4+f0], gateq[5+f0], gateq[6+f0], gateq[7+f0] };
    #pragma unroll
    for (int n = 0; n < 4; ++n) acc[m][n] = qv;
  }
  __syncthreads();                 // FT2 final for cross-wave L1 reads
  for (int c2 = 0; c2 < 8; ++c2) {
    const u16* wc = WB + (size_t)(3 + c2) * 8192;
    short8v af[4], bfr[4];
    #pragma unroll
    for (int m = 0; m < 4; ++m)
      af[m] = *(const short8v*)&wc[((Mw*4 + m)*64 + l)*8];
    #pragma unroll
    for (int n = 0; n < 4; ++n)
      bfr[n] = *(const short8v*)&FT2[((c2*8 + Nw*4 + n)*64 + l)*8];
    #pragma unroll
    for (int m = 0; m < 4; ++m)
      #pragma unroll
      for (int n = 0; n < 4; ++n)
        acc[m][n] = __builtin_amdgcn_mfma_f32_16x16x32_bf16(af[m], bfr[n], acc[m][n], 0, 0, 0);
  }

  // ===== layer 2 =====
  {
    float w2v[4][4];
    #pragma unroll
    for (int m = 0; m < 4; ++m) {
      int f0 = Mw*64 + m*16 + lg*4;
      #pragma unroll
      for (int r2 = 0; r2 < 4; ++r2) w2v[m][r2] = W2[f0 + r2];
    }
    #pragma unroll
    for (int n = 0; n < 4; ++n) {
      float p = 0.f;
      #pragma unroll
      for (int m = 0; m < 4; ++m)
        #pragma unroll
        for (int r2 = 0; r2 < 4; ++r2)
          p = fmaf(fmaxf(acc[m][n][r2], 0.f), w2v[m][r2], p);
      p += __shfl_xor(p, 16);
      p += __shfl_xor(p, 32);
      if (lg == 0) woacc[Mw][Nw*64 + n*16 + lr] = p;
    }
  }
  __syncthreads();
  if (t < 128) {
    int e = be + t;
    if (e < E)
      out[e] = woacc[0][t] + woacc[1][t] + woacc[2][t] + woacc[3][t] + b2[0];
  }
}

extern "C" void kernel_launch(void* const* d_in, const int* in_sizes, int n_in,
                              void* d_out, int out_size, void* d_ws, size_t ws_size,
                              hipStream_t stream) {
  const int*   h_id  = (const int*)  d_in[0];
  const int*   r_id  = (const int*)  d_in[1];
  const int*   t_id  = (const int*)  d_in[2];
  const float* q     = (const float*)d_in[3];
  const float* ent   = (const float*)d_in[4];
  const float* rel   = (const float*)d_in[6];
  const float* topic = (const float*)d_in[7];
  const int*   mids  = (const int*)  d_in[8];
  const float* mwts  = (const float*)d_in[9];
  const float* ntx   = (const float*)d_in[10];
  const float* motif = (const float*)d_in[11];
  const float* W_nb  = (const float*)d_in[12];
  const float* b_nb  = (const float*)d_in[13];
  const float* W_pos = (const float*)d_in[14];
  const float* b_pos = (const float*)d_in[15];
  const float* W_str = (const float*)d_in[16];
  const float* b_str = (const float*)d_in[17];
  const float* W_g   = (const float*)d_in[18];
  const float* b_g   = (const float*)d_in[19];
  const float* W1    = (const float*)d_in[20];
  const float* b1    = (const float*)d_in[21];
  const float* W2    = (const float*)d_in[22];
  const float* b2    = (const float*)d_in[23];
  float* out = (float*)d_out;

  const int E  = in_sizes[0];
  const int NT = in_sizes[4] / EMB;   // 80000 text entities
  const int N  = in_sizes[7] / 2;     // 100000 total nodes

  float* ws    = (float*)d_ws;
  float* cnt_f = ws;
  float* cnt_r = ws + (size_t)N;
  float* a1f   = ws + (size_t)2*N;
  float* a1r   = ws + (size_t)4*N;
  float* a2f   = ws + (size_t)6*N;
  float* a2r   = ws + (size_t)8*N;
  float* pos   = ws + (size_t)10*N;             // N x 10
  float* gateq = ws + (size_t)20*N;             // [g0,g1,g2,pad, qpart(256)]
  u16*   WB    = (u16*)(ws + (size_t)20*N + 512);   // 11 chunks x 8192 u16
  u16*   WN    = WB + (size_t)11*8192;              // 8*32*64*8 = 131072 u16
  float* S     = (float*)(WN + 131072);             // 2000*256 f32
  u16*   TA    = (u16*)(S + (size_t)2000*256);      // (NT+1) x 256 bf16
  u16*   TB    = TA + (size_t)(NT+1)*256;

  hipMemsetAsync(d_ws, 0, (size_t)10 * N * sizeof(float), stream);

  int gE = (E + 255) / 256, gN = (N + 255) / 256;
  int nNodeBlk = (NT + 64) / 64;
  k_scatter1 <<<gE, 256, 0, stream>>>(h_id, t_id, topic, cnt_f, cnt_r, a1f, a1r, E);
  k_div1_gate<<<gN + 1, 256, 0, stream>>>(topic, cnt_f, cnt_r, a1f, a1r, pos, N,
                                          q, W_g, b_g, W1, b1, gateq);
  k_scatter2 <<<gE, 256, 0, stream>>>(h_id, t_id, pos, a2f, a2r, E);
  k_div2     <<<gN, 256, 0, stream>>>(cnt_f, cnt_r, a2f, a2r, pos, N);
  k_wtrans   <<<108, 256, 0, stream>>>(W_pos, W_str, W1, W_nb, b_pos, gateq, WB, WN);
  k_node_S   <<<nNodeBlk + 1000, 512, 0, stream>>>(ent, ntx, WN, TA, TB, NT, nNodeBlk,
                                                   rel, W_str, b_nb, b_str, gateq, S);

  int gM = (E + 127) / 128;
  k_main<<<gM, 512, 0, stream>>>(h_id, r_id, t_id, mids, mwts, motif,
                                 W2, b2, pos, gateq, WB, S, TA, TB, out, E, NT);
}